// Round 13
// baseline (88.308 us; speedup 1.0000x reference)
//
#include <hip/hip_runtime.h>
#include <hip/hip_bf16.h>
#include <stdint.h>

// BERT self-attention fwd: B=2, S=2048, D=768, H=12, W=64. f32 in/out, bf16 MFMA inside.
// Stage 1: cvt x,Wq,Wk,Wv -> bf16.
// Stage 2: QKV projection GEMM (R6 structure): Q/K row-major (B,H,S,W), V^T (B,H,W,S).
// Stage 2.5: relayout_kv: K,V^T -> fragment-major K'/V' (XCD-affine: bh -> XCD bh%8).
// Stage 3: flash attention, barrier-free K-loop, XCD-affine. R13: QBLK=32, 4 waves each
//   own a QUARTER of the keys (16 tiles) -> grid 1536 (6 blocks/CU) for higher occupancy;
//   epilogue 4-way cross-wave reduce (waves 1-3 stage partial O in LDS, wave 0 finalizes).

typedef __attribute__((ext_vector_type(8))) short bf16x8;    // 8 bf16 = 4 VGPR (MFMA A/B frag)
typedef __attribute__((ext_vector_type(4))) float f32x4;     // 16x16 MFMA C/D frag
typedef __attribute__((ext_vector_type(16))) float f32x16;   // 32x32 MFMA C/D frag
typedef __attribute__((ext_vector_type(8))) unsigned short u16x8;

#define MFMA16(a, b, c) __builtin_amdgcn_mfma_f32_16x16x32_bf16((a), (b), (c), 0, 0, 0)
#define MFMA32(a, b, c) __builtin_amdgcn_mfma_f32_32x32x16_bf16((a), (b), (c), 0, 0, 0)
#define SWZ(row, colb) ((colb) ^ (((row) & 7) << 4))  // 128B-row swizzle

union U32x4BF {
  unsigned u[4];
  bf16x8 v;
};

__device__ __forceinline__ void gl_lds16(const void* g, void* l) {
  __builtin_amdgcn_global_load_lds(
      (__attribute__((address_space(1))) void*)const_cast<void*>(g),
      (__attribute__((address_space(3))) void*)l, 16, 0, 0);
}

__device__ __forceinline__ unsigned short f2bf(float x) {  // RNE f32->bf16
  unsigned int v = __float_as_uint(x);
  return (unsigned short)((v + 0x7fffu + ((v >> 16) & 1u)) >> 16);
}

// ---------------- Stage 1: f32 -> bf16 convert ----------------
__global__ __launch_bounds__(256) void cvt_all(
    const float* __restrict__ x, const float* __restrict__ wq,
    const float* __restrict__ wk, const float* __restrict__ wv,
    unsigned short* __restrict__ xb, unsigned short* __restrict__ wb) {
  int i = blockIdx.x * 256 + threadIdx.x;  // group-of-8 index; total 614400
  const float* s;
  unsigned short* d;
  int off;
  if (i < 393216)      { s = x;  d = xb;            off = i; }
  else if (i < 466944) { s = wq; d = wb;            off = i - 393216; }
  else if (i < 540672) { s = wk; d = wb + 589824;   off = i - 466944; }
  else                 { s = wv; d = wb + 1179648;  off = i - 540672; }
  const float4* sp = (const float4*)s + (size_t)off * 2;
  float4 a = sp[0], b2 = sp[1];
  u16x8 o;
  o[0] = f2bf(a.x); o[1] = f2bf(a.y); o[2] = f2bf(a.z); o[3] = f2bf(a.w);
  o[4] = f2bf(b2.x); o[5] = f2bf(b2.y); o[6] = f2bf(b2.z); o[7] = f2bf(b2.w);
  *((u16x8*)d + off) = o;
}

// ---------------- Stage 2: fused QKV projection (exact R6 structure) ----------------
__global__ __launch_bounds__(256) void proj_gemm(
    const unsigned short* __restrict__ xb, const unsigned short* __restrict__ wb,
    const float* __restrict__ bq, const float* __restrict__ bk, const float* __restrict__ bv,
    unsigned short* __restrict__ qw, unsigned short* __restrict__ kw,
    unsigned short* __restrict__ vw) {
  __shared__ __align__(16) char psmem[49152];  // 3 bufs x (A 8KB | B 8KB)
  const int t = threadIdx.x, lane = t & 63, wave = t >> 6;
  const int lo = lane & 15, hi = lane >> 4;  // hi in 0..3
  const int wr = wave >> 1, wc = wave & 1;   // 2x2 waves, 64x64 each
  const int mbase = blockIdx.x * 128;
  const int wsel = blockIdx.y / 6;
  const int nbase = (blockIdx.y % 6) * 128;
  const char* xc = (const char*)xb;
  const char* wmc = (const char*)(wb + (size_t)wsel * 589824);

  const int pp0 = t * 16, pp1 = t * 16 + 4096;
  const int ar0 = pp0 >> 7, ac0 = (pp0 & 127) ^ ((ar0 & 7) << 4);
  const int am0 = ((ac0 >> 6) << 6) + ar0, ak0 = ac0 & 63;
  const int ar1 = pp1 >> 7, ac1 = (pp1 & 127) ^ ((ar1 & 7) << 4);
  const int am1 = ((ac1 >> 6) << 6) + ar1, ak1 = ac1 & 63;

  const char* xa0 = xc + (size_t)(mbase + am0) * 1536 + ak0;
  const char* xa1 = xc + (size_t)(mbase + am1) * 1536 + ak1;
  const char* wa0 = wmc + (size_t)(nbase + am0) * 1536 + ak0;
  const char* wa1 = wmc + (size_t)(nbase + am1) * 1536 + ak1;

#define PSTAGE(BUF)                              \
  do {                                           \
    char* lb = psmem + (BUF) * 16384;            \
    gl_lds16(xa0, lb + pp0);                     \
    gl_lds16(xa1, lb + pp1);                     \
    gl_lds16(wa0, lb + 8192 + pp0);              \
    gl_lds16(wa1, lb + 8192 + pp1);              \
    xa0 += 64; xa1 += 64; wa0 += 64; wa1 += 64;  \
  } while (0)

  f32x4 acc[4][4];
#pragma unroll
  for (int i = 0; i < 4; i++)
#pragma unroll
    for (int j = 0; j < 4; j++) acc[i][j] = (f32x4){0.f, 0.f, 0.f, 0.f};

  const int axor = (lo & 7) << 4;
  PSTAGE(0);
  PSTAGE(1);
  int cur = 0, sb = 2;
#pragma unroll 1
  for (int it = 0; it < 24; ++it) {
    if (it < 22) {
      PSTAGE(sb);
      asm volatile("s_waitcnt vmcnt(8)" ::: "memory");
    } else if (it == 22) {
      asm volatile("s_waitcnt vmcnt(4)" ::: "memory");
    } else {
      asm volatile("s_waitcnt vmcnt(0)" ::: "memory");
    }
    __builtin_amdgcn_s_barrier();
    const char* lA = psmem + cur * 16384;
    const char* lB = lA + 8192;

    bf16x8 af[4], bf[4];
#pragma unroll
    for (int mf = 0; mf < 4; mf++)
      af[mf] = *(const bf16x8*)(lA + (mf * 16 + lo) * 128 + ((wr * 64 + hi * 16) ^ axor));
#pragma unroll
    for (int nf = 0; nf < 4; nf++)
      bf[nf] = *(const bf16x8*)(lB + (nf * 16 + lo) * 128 + ((wc * 64 + hi * 16) ^ axor));

    __builtin_amdgcn_s_setprio(1);
    if (wsel == 2) {  // V: operand-swapped -> acc holds C^T (rows=n, cols=m)
#pragma unroll
      for (int mf = 0; mf < 4; mf++)
#pragma unroll
        for (int nf = 0; nf < 4; nf++) acc[mf][nf] = MFMA16(bf[nf], af[mf], acc[mf][nf]);
    } else {
#pragma unroll
      for (int mf = 0; mf < 4; mf++)
#pragma unroll
        for (int nf = 0; nf < 4; nf++) acc[mf][nf] = MFMA16(af[mf], bf[nf], acc[mf][nf]);
    }
    __builtin_amdgcn_s_setprio(0);
    __builtin_amdgcn_s_barrier();  // trailing barrier: depth-2 with 3 bufs race-free
    cur = (cur == 2) ? 0 : cur + 1;
    sb = (sb == 2) ? 0 : sb + 1;
  }
#undef PSTAGE

  const float QSCALE = 0.125f * 1.44269504089f;  // fold 1/sqrt(64) * log2(e)
  if (wsel == 2) {
#pragma unroll
    for (int nf = 0; nf < 4; nf++) {
#pragma unroll
      for (int mf = 0; mf < 4; mf++) {
#pragma unroll
        for (int r = 0; r < 4; r++) {
          int n = nbase + wc * 64 + nf * 16 + hi * 4 + r;
          int m = mbase + wr * 64 + mf * 16 + lo;
          int b_ = m >> 11, s = m & 2047;
          int h = n >> 6, wcol = n & 63;
          float val = acc[mf][nf][r] + bv[n];
          vw[(((size_t)b_ * 12 + h) * 64 + wcol) * 2048 + s] = f2bf(val);
        }
      }
    }
  } else {
    const float* bias = (wsel == 0) ? bq : bk;
#pragma unroll
    for (int nf = 0; nf < 4; nf++) {
      int n = nbase + wc * 64 + nf * 16 + lo;
      float bv_ = bias[n];
      int h = n >> 6, wcol = n & 63;
#pragma unroll
      for (int mf = 0; mf < 4; mf++) {
#pragma unroll
        for (int r = 0; r < 4; r++) {
          int m = mbase + wr * 64 + mf * 16 + hi * 4 + r;
          int b_ = m >> 11, s = m & 2047;
          float val = acc[mf][nf][r] + bv_;
          size_t bhh = (size_t)b_ * 12 + h;
          if (wsel == 0)
            qw[(bhh * 2048 + s) * 64 + wcol] = f2bf(val * QSCALE);
          else
            kw[(bhh * 2048 + s) * 64 + wcol] = f2bf(val);
        }
      }
    }
  }
}

// ---------------- Stage 2.5: relayout K,V^T -> fragment-major K',V' ----------------
// grid 384 blocks, XCD-affine: bh -> XCD bh%8 (same mapping as attn).
__global__ __launch_bounds__(256) void relayout_kv(
    const unsigned short* kw, const unsigned short* __restrict__ vwT,
    unsigned short* __restrict__ kx, unsigned short* vx) {
  __shared__ __align__(16) char rsm[32768];  // [0,16K) K' image | [16K,32K) V' image
  const int t = threadIdx.x;
  const int bid = blockIdx.x;
  const int xcd = bid & 7, sidx = bid >> 3;      // sidx 0..47
  const int bh = xcd + 8 * (sidx % 3);           // bh -> XCD bh%8
  const int ktq = sidx / 3;                      // 0..15
  const size_t bhb = (size_t)bh * 262144;  // per-bh byte stride in all four arrays
  const int kt0 = ktq * 4;

  // K stage: thread reads K[key][d0..d0+8) (16B row-major chunk), writes 16B frag-major LDS
  {
    const int key = t >> 3;      // key-in-tile 0..31
    const int d0 = (t & 7) * 8;  // 0..56
    const char* ksrc = (const char*)kw + bhb + (size_t)kt0 * 4096 + key * 128 + d0 * 2;
    char* kldst = rsm + (d0 >> 4) * 1024 + ((d0 >> 3) & 1) * 512 + key * 16;
#pragma unroll
    for (int c = 0; c < 4; c++)
      *(u16x8*)(kldst + c * 4096) = *(const u16x8*)(ksrc + c * 4096);
  }
  // V stage: thread reads V^T[w][s0..s0+8) (16B s-contiguous), writes 16B frag-major LDS
  {
    const int w = t >> 2;         // 0..63
    const int sl0 = (t & 3) * 8;  // s-in-tile base 0,8,16,24
    const char* vsrc = (const char*)vwT + bhb + (size_t)w * 4096 + (kt0 * 32 + sl0) * 2;
    char* vldst = rsm + 16384 + (w >> 5) * 2048 + ((sl0 >> 4) & 1) * 1024 +
                  ((sl0 >> 3) & 1) * 512 + (w & 31) * 16;
#pragma unroll
    for (int c = 0; c < 4; c++)
      *(u16x8*)(vldst + c * 4096) = *(const u16x8*)(vsrc + c * 64);
  }
  __syncthreads();  // LDS images complete; all this block's kw reads drained

  // copy-out: both images are contiguous 16KB runs of the global arrays
  char* kdst = (char*)kx + bhb + (size_t)ktq * 16384;
  char* vdst = (char*)vx + bhb + (size_t)ktq * 16384;
#pragma unroll
  for (int c = 0; c < 4; c++) {
    int lb = c * 4096 + t * 16;
    *(u16x8*)(kdst + lb) = *(const u16x8*)(rsm + lb);
    *(u16x8*)(vdst + lb) = *(const u16x8*)(rsm + 16384 + lb);
  }
}

// ---------------- Stage 3: flash attention (barrier-free, QBLK=32, 4-way key split) ----
// grid 1536 blocks (flat), XCD-affine: sidx = bid>>3 (0..191), bh = (bid&7) + 8*(sidx%3),
// qb = sidx/3 (0..63). Block = 32 q-rows; wave wk (0..3) owns key tiles wk*16..wk*16+15.
__global__ __launch_bounds__(256) void attn_kernel(
    const unsigned short* __restrict__ qw, const unsigned short* __restrict__ kx,
    const unsigned short* __restrict__ vx, const int* __restrict__ mask,
    float* __restrict__ out) {
  // [0,24576): 3 partial-O slots (waves 1-3), [w][q] f32 swizzled, 8KB each
  // [24576,24832): ballot bytes | [24832,25344): lsum f32[32][4] (q-major float4)
  __shared__ __align__(16) char smem[25344];
  const int t = threadIdx.x, lane = t & 63, wk = t >> 6;
  const int l31 = lane & 31, hl = lane >> 5;
  const int bid = blockIdx.x;
  const int xcd = bid & 7, sidx = bid >> 3;   // sidx 0..191
  const int bh = xcd + 8 * (sidx % 3);        // bh -> XCD bh%8
  const int qb = sidx / 3;                    // 0..63 (32-row q tiles)
  const int b = bh / 12, hh = bh - b * 12;

  // bit-pack mask: thread t packs keys [t*8, t*8+8) -> ballot bytes
  {
    const int* mb = mask + (size_t)b * 2048 + t * 8;
    int4 a0 = *(const int4*)mb;
    int4 a1 = *(const int4*)(mb + 4);
    unsigned by = (unsigned)(a0.x != 0) | ((unsigned)(a0.y != 0) << 1) |
                  ((unsigned)(a0.z != 0) << 2) | ((unsigned)(a0.w != 0) << 3) |
                  ((unsigned)(a1.x != 0) << 4) | ((unsigned)(a1.y != 0) << 5) |
                  ((unsigned)(a1.z != 0) << 6) | ((unsigned)(a1.w != 0) << 7);
    smem[24576 + t] = (char)by;
  }
  __syncthreads();
  // lane i (i<16) holds the ballot of this wave's tile i
  const unsigned balv = *(const unsigned*)(smem + 24576 + (wk * 16 + (l31 & 15)) * 4);

  // Q B-frags: lane holds Q[q = l31][d = 16s + 8hl + j]
  bf16x8 qv[4];
  {
    int qrow = qb * 32 + l31;
    const char* qp = (const char*)qw + ((size_t)bh * 2048 + qrow) * 128 + hl * 16;
#pragma unroll
    for (int s = 0; s < 4; s++) qv[s] = *(const bf16x8*)(qp + s * 32);
  }

  // fragment stream pointers: wave wk owns 16 tiles starting at kt = wk*16
  const char* kp = (const char*)kx + (size_t)bh * 262144 + (size_t)wk * 65536 + lane * 16;
  const char* vp = (const char*)vx + (size_t)bh * 262144 + (size_t)wk * 65536 + lane * 16;

  f32x16 oacc[2];
#pragma unroll
  for (int wh = 0; wh < 2; wh++)
#pragma unroll
    for (int g = 0; g < 16; g++) oacc[wh][g] = 0.f;
  float lacc = 0.f;  // per-lane row-sum for q = l31 (this wave's hl slice)

  // prologue: K(0) fragments
  bf16x8 ka0 = *(const bf16x8*)(kp);
  bf16x8 ka1 = *(const bf16x8*)(kp + 1024);
  bf16x8 ka2 = *(const bf16x8*)(kp + 2048);
  bf16x8 ka3 = *(const bf16x8*)(kp + 3072);
  kp += 4096;

#pragma unroll 2
  for (int it = 0; it < 16; ++it) {
    // issue V(it) early (consumed after softmax)
    bf16x8 v00 = *(const bf16x8*)(vp);          // wh0 sp0
    bf16x8 v01 = *(const bf16x8*)(vp + 1024);   // wh0 sp1
    bf16x8 v10 = *(const bf16x8*)(vp + 2048);   // wh1 sp0
    bf16x8 v11 = *(const bf16x8*)(vp + 3072);   // wh1 sp1
    vp += 4096;

    // QK^T swapped: sc[g] = S^T[key-in-tile = (g&3)+8(g>>2)+4hl][q = l31]
    f32x16 sc;
#pragma unroll
    for (int g = 0; g < 16; g++) sc[g] = 0.f;
    __builtin_amdgcn_s_setprio(1);
    sc = MFMA32(ka0, qv[0], sc);
    sc = MFMA32(ka1, qv[1], sc);
    sc = MFMA32(ka2, qv[2], sc);
    sc = MFMA32(ka3, qv[3], sc);
    __builtin_amdgcn_s_setprio(0);

    // prefetch K(it+1); at it=15 this harmlessly reads adjacent valid memory
    ka0 = *(const bf16x8*)(kp);
    ka1 = *(const bf16x8*)(kp + 1024);
    ka2 = *(const bf16x8*)(kp + 2048);
    ka3 = *(const bf16x8*)(kp + 3072);
    kp += 4096;

    // mask (uniform skip when all-ones)
    unsigned bal = __builtin_amdgcn_readlane(balv, it);
    if (bal != 0xFFFFFFFFu) {
#pragma unroll
      for (int g = 0; g < 16; g++) {
        int key = (g & 3) + 8 * (g >> 2) + 4 * hl;
        if (!((bal >> key) & 1)) sc[g] = -30000.f;  // exp2 -> 0
      }
    }

    // P = exp2(sc) in place; pack to bf16 A-frags
#pragma unroll
    for (int g = 0; g < 16; g++) {
      float e_;
      asm("v_exp_f32 %0, %1" : "=v"(e_) : "v"(sc[g]));
      sc[g] = e_;
    }
    unsigned pk[4][2];
#pragma unroll
    for (int m = 0; m < 4; m++) {
      asm("v_cvt_pk_bf16_f32 %0, %1, %2" : "=v"(pk[m][0]) : "v"(sc[4 * m]), "v"(sc[4 * m + 1]));
      asm("v_cvt_pk_bf16_f32 %0, %1, %2" : "=v"(pk[m][1]) : "v"(sc[4 * m + 2]), "v"(sc[4 * m + 3]));
    }
    U32x4BF apv[2];  // A[q=l31][k_local = 16sp + 8hl + j]
#pragma unroll
    for (int sp = 0; sp < 2; sp++)
#pragma unroll
      for (int cp = 0; cp < 2; cp++) {
        unsigned xx = pk[2 * sp][cp], yy = pk[2 * sp + 1][cp];
        asm("v_permlane32_swap_b32 %0, %1" : "+v"(xx), "+v"(yy));
        apv[sp].u[cp] = xx;
        apv[sp].u[2 + cp] = yy;
      }

    // PV: oacc[wh] += P(32q x 32k) @ V(32k x 32w)
    __builtin_amdgcn_s_setprio(1);
    oacc[0] = MFMA32(apv[0].v, v00, oacc[0]);
    oacc[0] = MFMA32(apv[1].v, v01, oacc[0]);
    oacc[1] = MFMA32(apv[0].v, v10, oacc[1]);
    oacc[1] = MFMA32(apv[1].v, v11, oacc[1]);
    __builtin_amdgcn_s_setprio(0);

    // row-sum adds AFTER PV issue (VALU overlaps MFMA pipe)
    lacc += (((sc[0] + sc[1]) + (sc[2] + sc[3])) + ((sc[4] + sc[5]) + (sc[6] + sc[7]))) +
            (((sc[8] + sc[9]) + (sc[10] + sc[11])) + ((sc[12] + sc[13]) + (sc[14] + sc[15])));
  }

  // ---- epilogue: 4-way cross-wave reduce of O and l, then out = O / l ----
  lacc += __shfl_xor(lacc, 32);  // combine hl halves; lanes <32 hold sum for q=l31
  if (lane < 32)
    *(float*)(smem + 24832 + (l31 * 4 + wk) * 4) = lacc;  // lsum[q][wk]
  if (wk > 0) {  // waves 1-3 stage partial O as [w][q] f32 (swizzled rows)
#pragma unroll
    for (int wh = 0; wh < 2; wh++) {
      int vrow = wh * 32 + l31;
#pragma unroll
      for (int m = 0; m < 4; m++) {
        f32x4 part = (f32x4){oacc[wh][4 * m], oacc[wh][4 * m + 1],
                             oacc[wh][4 * m + 2], oacc[wh][4 * m + 3]};
        *(f32x4*)(smem + (wk - 1) * 8192 + vrow * 128 + SWZ(vrow, hl * 16 + m * 32)) = part;
      }
    }
  }
  __syncthreads();
  if (wk == 0) {
    float linv[16];
#pragma unroll
    for (int g = 0; g < 16; g++) {
      int qrow = 4 * hl + (g & 3) + 8 * (g >> 2);
      float4 lp = *(const float4*)(smem + 24832 + qrow * 16);
      linv[g] = __builtin_amdgcn_rcpf((lp.x + lp.y) + (lp.z + lp.w));
    }
#pragma unroll
    for (int wh = 0; wh < 2; wh++) {
      int vrow = wh * 32 + l31;
#pragma unroll
      for (int m = 0; m < 4; m++) {
        f32x4 p0 = *(const f32x4*)(smem + vrow * 128 + SWZ(vrow, hl * 16 + m * 32));
        f32x4 p1 = *(const f32x4*)(smem + 8192 + vrow * 128 + SWZ(vrow, hl * 16 + m * 32));
        f32x4 p2 = *(const f32x4*)(smem + 16384 + vrow * 128 + SWZ(vrow, hl * 16 + m * 32));
#pragma unroll
        for (int r = 0; r < 4; r++) {
          int g = 4 * m + r;
          int qrow = 4 * hl + r + 8 * m;
          float val = (oacc[wh][g] + ((p0[r] + p1[r]) + p2[r])) * linv[g];
          out[((size_t)b * 2048 + qb * 32 + qrow) * 768 + hh * 64 + wh * 32 + l31] = val;
        }
      }
    }
  }
}

// ---------------- launch ----------------
extern "C" void kernel_launch(void* const* d_in, const int* in_sizes, int n_in,
                              void* d_out, int out_size, void* d_ws, size_t ws_size,
                              hipStream_t stream) {
  (void)in_sizes; (void)n_in; (void)out_size; (void)ws_size;
  const float* x  = (const float*)d_in[0];
  const float* Wq = (const float*)d_in[1];
  const float* bq = (const float*)d_in[2];
  const float* Wk = (const float*)d_in[3];
  const float* bk = (const float*)d_in[4];
  const float* Wv = (const float*)d_in[5];
  const float* bv = (const float*)d_in[6];
  const int* mask = (const int*)d_in[7];
  float* out = (float*)d_out;

  char* ws = (char*)d_ws;
  unsigned short* xb  = (unsigned short*)(ws);             // 4096x768 bf16 (6291456 B)
  unsigned short* wb  = (unsigned short*)(ws + 6291456);   // 3x 768x768 bf16 (3538944 B)
  unsigned short* qw  = (unsigned short*)(ws + 9830400);   // Q (B,H,S,W)
  unsigned short* kw  = (unsigned short*)(ws + 16121856);  // K (B,H,S,W) [pre-relayout]
  unsigned short* vwT = (unsigned short*)(ws + 22413312);  // V^T (B,H,W,S)
  unsigned short* kx  = (unsigned short*)(ws);             // K' frag-major (over xb, dead)
  unsigned short* vx  = (unsigned short*)(ws + 16121856);  // V' frag-major (over kw, dead)

  cvt_all<<<2400, 256, 0, stream>>>(x, Wq, Wk, Wv, xb, wb);
  proj_gemm<<<dim3(32, 18), 256, 0, stream>>>(xb, wb, bq, bk, bv, qw, kw, vwT);
  relayout_kv<<<384, 256, 0, stream>>>(kw, vwT, kx, vx);
  attn_kernel<<<1536, 256, 0, stream>>>(qw, kx, vx, mask, out);
}

// Round 14
// 83.211 us; speedup vs baseline: 1.0613x; 1.0613x over previous
//
#include <hip/hip_runtime.h>
#include <hip/hip_bf16.h>
#include <stdint.h>

// BERT self-attention fwd: B=2, S=2048, D=768, H=12, W=64. f32 in/out, bf16 MFMA inside.
// Stage 1: cvt x,Wq,Wk,Wv -> bf16.
// Stage 2: QKV projection GEMM, 64x128 tile (R14: 1152 blocks for occupancy), BK=32,
//   3-buf LDS, depth-2 prefetch (vmcnt 6/3/0), 2 barriers/iter. Q/K row-major, V^T.
// Stage 2.5: relayout_kv: K,V^T -> fragment-major K'/V' (XCD-affine: bh -> XCD bh%8).
// Stage 3: flash attention (R12): barrier-free K-loop, XCD-affine, 64 q-rows/block,
//   waves = (wq q-half x wk key-half), K'/V' streamed global->VGPR coalesced.

typedef __attribute__((ext_vector_type(8))) short bf16x8;    // 8 bf16 = 4 VGPR (MFMA A/B frag)
typedef __attribute__((ext_vector_type(4))) float f32x4;     // 16x16 MFMA C/D frag
typedef __attribute__((ext_vector_type(16))) float f32x16;   // 32x32 MFMA C/D frag
typedef __attribute__((ext_vector_type(8))) unsigned short u16x8;

#define MFMA16(a, b, c) __builtin_amdgcn_mfma_f32_16x16x32_bf16((a), (b), (c), 0, 0, 0)
#define MFMA32(a, b, c) __builtin_amdgcn_mfma_f32_32x32x16_bf16((a), (b), (c), 0, 0, 0)
#define SWZ(row, colb) ((colb) ^ (((row) & 7) << 4))  // 128B-row swizzle

union U32x4BF {
  unsigned u[4];
  bf16x8 v;
};

__device__ __forceinline__ void gl_lds16(const void* g, void* l) {
  __builtin_amdgcn_global_load_lds(
      (__attribute__((address_space(1))) void*)const_cast<void*>(g),
      (__attribute__((address_space(3))) void*)l, 16, 0, 0);
}

__device__ __forceinline__ unsigned short f2bf(float x) {  // RNE f32->bf16
  unsigned int v = __float_as_uint(x);
  return (unsigned short)((v + 0x7fffu + ((v >> 16) & 1u)) >> 16);
}

// ---------------- Stage 1: f32 -> bf16 convert ----------------
__global__ __launch_bounds__(256) void cvt_all(
    const float* __restrict__ x, const float* __restrict__ wq,
    const float* __restrict__ wk, const float* __restrict__ wv,
    unsigned short* __restrict__ xb, unsigned short* __restrict__ wb) {
  int i = blockIdx.x * 256 + threadIdx.x;  // group-of-8 index; total 614400
  const float* s;
  unsigned short* d;
  int off;
  if (i < 393216)      { s = x;  d = xb;            off = i; }
  else if (i < 466944) { s = wq; d = wb;            off = i - 393216; }
  else if (i < 540672) { s = wk; d = wb + 589824;   off = i - 466944; }
  else                 { s = wv; d = wb + 1179648;  off = i - 540672; }
  const float4* sp = (const float4*)s + (size_t)off * 2;
  float4 a = sp[0], b2 = sp[1];
  u16x8 o;
  o[0] = f2bf(a.x); o[1] = f2bf(a.y); o[2] = f2bf(a.z); o[3] = f2bf(a.w);
  o[4] = f2bf(b2.x); o[5] = f2bf(b2.y); o[6] = f2bf(b2.z); o[7] = f2bf(b2.w);
  *((u16x8*)d + off) = o;
}

// ---------------- Stage 2: fused QKV projection (64x128 tile, BK=32) ----------------
// grid (64, 18): mbase = bx*64; y/6 = wsel, y%6 = n-tile. Block = 4 waves, wave w owns
// n-strip [w*32, w*32+32). LDS buf 12KB: A image 4KB [32][128B] (m = (c>>6)*32 + r),
// B image 8KB [64][128B] (n = (c>>6)*64 + r); both XOR-swizzled ((r&7)<<4).
__global__ __launch_bounds__(256) void proj_gemm(
    const unsigned short* __restrict__ xb, const unsigned short* __restrict__ wb,
    const float* __restrict__ bq, const float* __restrict__ bk, const float* __restrict__ bv,
    unsigned short* __restrict__ qw, unsigned short* __restrict__ kw,
    unsigned short* __restrict__ vw) {
  __shared__ __align__(16) char psmem[36864];  // 3 bufs x (A 4KB | B 8KB)
  const int t = threadIdx.x, lane = t & 63, w = t >> 6;
  const int lo = lane & 15, hi = lane >> 4;  // hi in 0..3
  const int mbase = blockIdx.x * 64;
  const int wsel = blockIdx.y / 6;
  const int nbase = (blockIdx.y % 6) * 128;
  const char* xc = (const char*)xb;
  const char* wmc = (const char*)(wb + (size_t)wsel * 589824);

  // staging decode: A chunk (1 per thread), B chunks (2 per thread)
  const int tA = t * 16;
  const int arA = tA >> 7, acA = (tA & 127) ^ ((arA & 7) << 4);
  const int mA = ((acA >> 6) << 5) + arA, kA = acA & 63;
  const int pB0 = t * 16, pB1 = t * 16 + 4096;
  const int rB0 = pB0 >> 7, cB0 = (pB0 & 127) ^ ((rB0 & 7) << 4);
  const int nB0 = ((cB0 >> 6) << 6) + rB0, kB0 = cB0 & 63;
  const int rB1 = pB1 >> 7, cB1 = (pB1 & 127) ^ ((rB1 & 7) << 4);
  const int nB1 = ((cB1 >> 6) << 6) + rB1, kB1 = cB1 & 63;

  const char* xa0 = xc + (size_t)(mbase + mA) * 1536 + kA;
  const char* wa0 = wmc + (size_t)(nbase + nB0) * 1536 + kB0;
  const char* wa1 = wmc + (size_t)(nbase + nB1) * 1536 + kB1;

#define PSTAGE(BUF)                              \
  do {                                           \
    char* lb = psmem + (BUF) * 12288;            \
    gl_lds16(xa0, lb + tA);                      \
    gl_lds16(wa0, lb + 4096 + pB0);              \
    gl_lds16(wa1, lb + 4096 + pB1);              \
    xa0 += 64; wa0 += 64; wa1 += 64;             \
  } while (0)

  f32x4 acc[4][2];
#pragma unroll
  for (int i = 0; i < 4; i++)
#pragma unroll
    for (int j = 0; j < 2; j++) acc[i][j] = (f32x4){0.f, 0.f, 0.f, 0.f};

  PSTAGE(0);
  PSTAGE(1);
  int cur = 0, sb = 2;
#pragma unroll 1
  for (int it = 0; it < 24; ++it) {
    if (it < 22) {
      PSTAGE(sb);
      asm volatile("s_waitcnt vmcnt(6)" ::: "memory");
    } else if (it == 22) {
      asm volatile("s_waitcnt vmcnt(3)" ::: "memory");
    } else {
      asm volatile("s_waitcnt vmcnt(0)" ::: "memory");
    }
    __builtin_amdgcn_s_barrier();
    const char* lA = psmem + cur * 12288;
    const char* lB = lA + 4096;

    bf16x8 af[4], bf[2];
#pragma unroll
    for (int mf = 0; mf < 4; mf++) {
      int row = mf * 16 + lo;  // 0..63
      af[mf] = *(const bf16x8*)(lA + (row & 31) * 128 +
                                ((((row >> 5) << 6) + hi * 16) ^ ((row & 7) << 4)));
    }
#pragma unroll
    for (int nf = 0; nf < 2; nf++) {
      int n = w * 32 + nf * 16 + lo;  // 0..127
      bf[nf] = *(const bf16x8*)(lB + (n & 63) * 128 +
                                ((((n >> 6) << 6) + hi * 16) ^ ((n & 7) << 4)));
    }

    __builtin_amdgcn_s_setprio(1);
    if (wsel == 2) {  // V: operand-swapped -> acc holds C^T (rows=n, cols=m)
#pragma unroll
      for (int mf = 0; mf < 4; mf++)
#pragma unroll
        for (int nf = 0; nf < 2; nf++) acc[mf][nf] = MFMA16(bf[nf], af[mf], acc[mf][nf]);
    } else {
#pragma unroll
      for (int mf = 0; mf < 4; mf++)
#pragma unroll
        for (int nf = 0; nf < 2; nf++) acc[mf][nf] = MFMA16(af[mf], bf[nf], acc[mf][nf]);
    }
    __builtin_amdgcn_s_setprio(0);
    __builtin_amdgcn_s_barrier();  // trailing barrier: depth-2 with 3 bufs race-free
    cur = (cur == 2) ? 0 : cur + 1;
    sb = (sb == 2) ? 0 : sb + 1;
  }
#undef PSTAGE

  const float QSCALE = 0.125f * 1.44269504089f;  // fold 1/sqrt(64) * log2(e)
  if (wsel == 2) {
#pragma unroll
    for (int nf = 0; nf < 2; nf++) {
#pragma unroll
      for (int mf = 0; mf < 4; mf++) {
#pragma unroll
        for (int r = 0; r < 4; r++) {
          int n = nbase + w * 32 + nf * 16 + hi * 4 + r;
          int m = mbase + mf * 16 + lo;
          int b_ = m >> 11, s = m & 2047;
          int h = n >> 6, wcol = n & 63;
          float val = acc[mf][nf][r] + bv[n];
          vw[(((size_t)b_ * 12 + h) * 64 + wcol) * 2048 + s] = f2bf(val);
        }
      }
    }
  } else {
    const float* bias = (wsel == 0) ? bq : bk;
#pragma unroll
    for (int nf = 0; nf < 2; nf++) {
      int n = nbase + w * 32 + nf * 16 + lo;
      float bv_ = bias[n];
      int h = n >> 6, wcol = n & 63;
#pragma unroll
      for (int mf = 0; mf < 4; mf++) {
#pragma unroll
        for (int r = 0; r < 4; r++) {
          int m = mbase + mf * 16 + hi * 4 + r;
          int b_ = m >> 11, s = m & 2047;
          float val = acc[mf][nf][r] + bv_;
          size_t bhh = (size_t)b_ * 12 + h;
          if (wsel == 0)
            qw[(bhh * 2048 + s) * 64 + wcol] = f2bf(val * QSCALE);
          else
            kw[(bhh * 2048 + s) * 64 + wcol] = f2bf(val);
        }
      }
    }
  }
}

// ---------------- Stage 2.5: relayout K,V^T -> fragment-major K',V' ----------------
// grid 384 blocks, XCD-affine: bh -> XCD bh%8 (same mapping as attn).
__global__ __launch_bounds__(256) void relayout_kv(
    const unsigned short* kw, const unsigned short* __restrict__ vwT,
    unsigned short* __restrict__ kx, unsigned short* vx) {
  __shared__ __align__(16) char rsm[32768];  // [0,16K) K' image | [16K,32K) V' image
  const int t = threadIdx.x;
  const int bid = blockIdx.x;
  const int xcd = bid & 7, sidx = bid >> 3;      // sidx 0..47
  const int bh = xcd + 8 * (sidx % 3);           // bh -> XCD bh%8
  const int ktq = sidx / 3;                      // 0..15
  const size_t bhb = (size_t)bh * 262144;  // per-bh byte stride in all four arrays
  const int kt0 = ktq * 4;

  // K stage: thread reads K[key][d0..d0+8) (16B row-major chunk), writes 16B frag-major LDS
  {
    const int key = t >> 3;      // key-in-tile 0..31
    const int d0 = (t & 7) * 8;  // 0..56
    const char* ksrc = (const char*)kw + bhb + (size_t)kt0 * 4096 + key * 128 + d0 * 2;
    char* kldst = rsm + (d0 >> 4) * 1024 + ((d0 >> 3) & 1) * 512 + key * 16;
#pragma unroll
    for (int c = 0; c < 4; c++)
      *(u16x8*)(kldst + c * 4096) = *(const u16x8*)(ksrc + c * 4096);
  }
  // V stage: thread reads V^T[w][s0..s0+8) (16B s-contiguous), writes 16B frag-major LDS
  {
    const int w = t >> 2;         // 0..63
    const int sl0 = (t & 3) * 8;  // s-in-tile base 0,8,16,24
    const char* vsrc = (const char*)vwT + bhb + (size_t)w * 4096 + (kt0 * 32 + sl0) * 2;
    char* vldst = rsm + 16384 + (w >> 5) * 2048 + ((sl0 >> 4) & 1) * 1024 +
                  ((sl0 >> 3) & 1) * 512 + (w & 31) * 16;
#pragma unroll
    for (int c = 0; c < 4; c++)
      *(u16x8*)(vldst + c * 4096) = *(const u16x8*)(vsrc + c * 64);
  }
  __syncthreads();  // LDS images complete; all this block's kw reads drained

  // copy-out: both images are contiguous 16KB runs of the global arrays
  char* kdst = (char*)kx + bhb + (size_t)ktq * 16384;
  char* vdst = (char*)vx + bhb + (size_t)ktq * 16384;
#pragma unroll
  for (int c = 0; c < 4; c++) {
    int lb = c * 4096 + t * 16;
    *(u16x8*)(kdst + lb) = *(const u16x8*)(rsm + lb);
    *(u16x8*)(vdst + lb) = *(const u16x8*)(rsm + 16384 + lb);
  }
}

// ---------------- Stage 3: flash attention (R12: barrier-free, XCD-affine) ----------------
// grid 768 blocks (flat): all 32 q-blocks of a bh land on XCD bh%8 -> that bh's 512KB
// K'/V' is L2-resident. Block = 64 q-rows, waves = (wq q-half x wk key-half).
__global__ __launch_bounds__(256) void attn_kernel(
    const unsigned short* __restrict__ qw, const unsigned short* __restrict__ kx,
    const unsigned short* __restrict__ vx, const int* __restrict__ mask,
    float* __restrict__ out) {
  // [0,16384) epilogue O-staging (2 wq x 8KB) | [16384,16640) ballot bytes |
  // [16640,17152) lsum f32[128]: ((wq*32+q)*2 + wk)
  __shared__ __align__(16) char smem[17152];
  const int t = threadIdx.x, lane = t & 63, wave = t >> 6;
  const int wq = wave >> 1, wk = wave & 1;
  const int l31 = lane & 31, hl = lane >> 5;
  const int bid = blockIdx.x;
  const int xcd = bid & 7, sidx = bid >> 3;   // sidx 0..95
  const int bh = xcd + 8 * (sidx % 3);        // bh -> XCD bh%8
  const int qb = sidx / 3;                    // 0..31
  const int b = bh / 12, hh = bh - b * 12;

  // bit-pack mask: thread t packs keys [t*8, t*8+8) -> ballot bytes
  {
    const int* mb = mask + (size_t)b * 2048 + t * 8;
    int4 a0 = *(const int4*)mb;
    int4 a1 = *(const int4*)(mb + 4);
    unsigned by = (unsigned)(a0.x != 0) | ((unsigned)(a0.y != 0) << 1) |
                  ((unsigned)(a0.z != 0) << 2) | ((unsigned)(a0.w != 0) << 3) |
                  ((unsigned)(a1.x != 0) << 4) | ((unsigned)(a1.y != 0) << 5) |
                  ((unsigned)(a1.z != 0) << 6) | ((unsigned)(a1.w != 0) << 7);
    smem[16384 + t] = (char)by;
  }
  __syncthreads();
  // lane i holds the 32-key ballot of this wave's tile (i&31)
  const unsigned balv = *(const unsigned*)(smem + 16384 + (wk * 32 + l31) * 4);

  // Q B-frags: lane holds Q[q = l31 of wq-half][d = 16s + 8hl + j]
  bf16x8 qv[4];
  {
    int qrow = qb * 64 + wq * 32 + l31;
    const char* qp = (const char*)qw + ((size_t)bh * 2048 + qrow) * 128 + hl * 16;
#pragma unroll
    for (int s = 0; s < 4; s++) qv[s] = *(const bf16x8*)(qp + s * 32);
  }

  // fragment stream pointers (coalesced: lane*16 within 1KB chunks)
  const char* kp = (const char*)kx + (size_t)bh * 262144 + (size_t)wk * 131072 + lane * 16;
  const char* vp = (const char*)vx + (size_t)bh * 262144 + (size_t)wk * 131072 + lane * 16;

  f32x16 oacc[2];
#pragma unroll
  for (int wh = 0; wh < 2; wh++)
#pragma unroll
    for (int g = 0; g < 16; g++) oacc[wh][g] = 0.f;
  float lacc = 0.f;  // per-lane row-sum for q = l31 (this wave's hl/wk slice)

  // prologue: K(0) fragments
  bf16x8 ka0 = *(const bf16x8*)(kp);
  bf16x8 ka1 = *(const bf16x8*)(kp + 1024);
  bf16x8 ka2 = *(const bf16x8*)(kp + 2048);
  bf16x8 ka3 = *(const bf16x8*)(kp + 3072);
  kp += 4096;

#pragma unroll 2
  for (int it = 0; it < 32; ++it) {
    // issue V(it) early (consumed after softmax)
    bf16x8 v00 = *(const bf16x8*)(vp);          // wh0 sp0
    bf16x8 v01 = *(const bf16x8*)(vp + 1024);   // wh0 sp1
    bf16x8 v10 = *(const bf16x8*)(vp + 2048);   // wh1 sp0
    bf16x8 v11 = *(const bf16x8*)(vp + 3072);   // wh1 sp1
    vp += 4096;

    // QK^T swapped: sc[g] = S^T[key-in-tile = (g&3)+8(g>>2)+4hl][q = l31]
    f32x16 sc;
#pragma unroll
    for (int g = 0; g < 16; g++) sc[g] = 0.f;
    __builtin_amdgcn_s_setprio(1);
    sc = MFMA32(ka0, qv[0], sc);
    sc = MFMA32(ka1, qv[1], sc);
    sc = MFMA32(ka2, qv[2], sc);
    sc = MFMA32(ka3, qv[3], sc);
    __builtin_amdgcn_s_setprio(0);

    // prefetch K(it+1); at it=31 this harmlessly reads adjacent valid memory
    ka0 = *(const bf16x8*)(kp);
    ka1 = *(const bf16x8*)(kp + 1024);
    ka2 = *(const bf16x8*)(kp + 2048);
    ka3 = *(const bf16x8*)(kp + 3072);
    kp += 4096;

    // mask (uniform skip when all-ones)
    unsigned bal = __builtin_amdgcn_readlane(balv, it);
    if (bal != 0xFFFFFFFFu) {
#pragma unroll
      for (int g = 0; g < 16; g++) {
        int key = (g & 3) + 8 * (g >> 2) + 4 * hl;
        if (!((bal >> key) & 1)) sc[g] = -30000.f;  // exp2 -> 0
      }
    }

    // P = exp2(sc) in place; pack to bf16 A-frags
#pragma unroll
    for (int g = 0; g < 16; g++) {
      float e_;
      asm("v_exp_f32 %0, %1" : "=v"(e_) : "v"(sc[g]));
      sc[g] = e_;
    }
    unsigned pk[4][2];
#pragma unroll
    for (int m = 0; m < 4; m++) {
      asm("v_cvt_pk_bf16_f32 %0, %1, %2" : "=v"(pk[m][0]) : "v"(sc[4 * m]), "v"(sc[4 * m + 1]));
      asm("v_cvt_pk_bf16_f32 %0, %1, %2" : "=v"(pk[m][1]) : "v"(sc[4 * m + 2]), "v"(sc[4 * m + 3]));
    }
    U32x4BF apv[2];  // A[q=l31][k_local = 16sp + 8hl + j]
#pragma unroll
    for (int sp = 0; sp < 2; sp++)
#pragma unroll
      for (int cp = 0; cp < 2; cp++) {
        unsigned xx = pk[2 * sp][cp], yy = pk[2 * sp + 1][cp];
        asm("v_permlane32_swap_b32 %0, %1" : "+v"(xx), "+v"(yy));
        apv[sp].u[cp] = xx;
        apv[sp].u[2 + cp] = yy;
      }

    // PV: oacc[wh] += P(32q x 32k) @ V(32k x 32w)
    __builtin_amdgcn_s_setprio(1);
    oacc[0] = MFMA32(apv[0].v, v00, oacc[0]);
    oacc[0] = MFMA32(apv[1].v, v01, oacc[0]);
    oacc[1] = MFMA32(apv[0].v, v10, oacc[1]);
    oacc[1] = MFMA32(apv[1].v, v11, oacc[1]);
    __builtin_amdgcn_s_setprio(0);

    // row-sum adds AFTER PV issue: VALU overlaps MFMA pipe (deps: exp results only)
    lacc += (((sc[0] + sc[1]) + (sc[2] + sc[3])) + ((sc[4] + sc[5]) + (sc[6] + sc[7]))) +
            (((sc[8] + sc[9]) + (sc[10] + sc[11])) + ((sc[12] + sc[13]) + (sc[14] + sc[15])));
  }

  // ---- epilogue: cross-wk reduce of O and l, then out = O / l ----
  lacc += __shfl_xor(lacc, 32);  // combine hl halves; all lanes hold sum for q=l31 (wk half)
  if (lane < 32)
    *(float*)(smem + 16640 + (((wq * 32 + l31) << 1) + wk) * 4) = lacc;
  if (wk == 1) {  // partial O as [w][q] f32 into [0,16384)
#pragma unroll
    for (int wh = 0; wh < 2; wh++) {
      int vrow = wh * 32 + l31;
#pragma unroll
      for (int m = 0; m < 4; m++) {
        f32x4 part = (f32x4){oacc[wh][4 * m], oacc[wh][4 * m + 1],
                             oacc[wh][4 * m + 2], oacc[wh][4 * m + 3]};
        *(f32x4*)(smem + wq * 8192 + vrow * 128 + SWZ(vrow, hl * 16 + m * 32)) = part;
      }
    }
  }
  __syncthreads();
  if (wk == 0) {
    float linv[16];
#pragma unroll
    for (int g = 0; g < 16; g++) {
      int qrow = 4 * hl + (g & 3) + 8 * (g >> 2);
      float2 lp = *(const float2*)(smem + 16640 + ((wq * 32 + qrow) << 3));
      linv[g] = __builtin_amdgcn_rcpf(lp.x + lp.y);
    }
#pragma unroll
    for (int wh = 0; wh < 2; wh++) {
      int vrow = wh * 32 + l31;
#pragma unroll
      for (int m = 0; m < 4; m++) {
        f32x4 part = *(const f32x4*)(smem + wq * 8192 + vrow * 128 + SWZ(vrow, hl * 16 + m * 32));
#pragma unroll
        for (int r = 0; r < 4; r++) {
          int g = 4 * m + r;
          int qrow = 4 * hl + r + 8 * m;
          float val = (oacc[wh][g] + part[r]) * linv[g];
          out[((size_t)b * 2048 + qb * 64 + wq * 32 + qrow) * 768 + hh * 64 + wh * 32 + l31] =
              val;
        }
      }
    }
  }
}

// ---------------- launch ----------------
extern "C" void kernel_launch(void* const* d_in, const int* in_sizes, int n_in,
                              void* d_out, int out_size, void* d_ws, size_t ws_size,
                              hipStream_t stream) {
  (void)in_sizes; (void)n_in; (void)out_size; (void)ws_size;
  const float* x  = (const float*)d_in[0];
  const float* Wq = (const float*)d_in[1];
  const float* bq = (const float*)d_in[2];
  const float* Wk = (const float*)d_in[3];
  const float* bk = (const float*)d_in[4];
  const float* Wv = (const float*)d_in[5];
  const float* bv = (const float*)d_in[6];
  const int* mask = (const int*)d_in[7];
  float* out = (float*)d_out;

  char* ws = (char*)d_ws;
  unsigned short* xb  = (unsigned short*)(ws);             // 4096x768 bf16 (6291456 B)
  unsigned short* wb  = (unsigned short*)(ws + 6291456);   // 3x 768x768 bf16 (3538944 B)
  unsigned short* qw  = (unsigned short*)(ws + 9830400);   // Q (B,H,S,W)
  unsigned short* kw  = (unsigned short*)(ws + 16121856);  // K (B,H,S,W) [pre-relayout]
  unsigned short* vwT = (unsigned short*)(ws + 22413312);  // V^T (B,H,W,S)
  unsigned short* kx  = (unsigned short*)(ws);             // K' frag-major (over xb, dead)
  unsigned short* vx  = (unsigned short*)(ws + 16121856);  // V' frag-major (over kw, dead)

  cvt_all<<<2400, 256, 0, stream>>>(x, Wq, Wk, Wv, xb, wb);
  proj_gemm<<<dim3(64, 18), 256, 0, stream>>>(xb, wb, bq, bk, bv, qw, kw, vwT);
  relayout_kv<<<384, 256, 0, stream>>>(kw, vwT, kx, vx);
  attn_kernel<<<768, 256, 0, stream>>>(qw, kx, vx, mask, out);
}

// Round 15
// 82.538 us; speedup vs baseline: 1.0699x; 1.0082x over previous
//
#include <hip/hip_runtime.h>
#include <hip/hip_bf16.h>
#include <stdint.h>

// BERT self-attention fwd: B=2, S=2048, D=768, H=12, W=64. f32 in/out, bf16 MFMA inside.
// Stage 1: cvt x,Wq,Wk,Wv -> bf16.
// Stage 2: QKV projection GEMM, 64x128 tile, BK=32, 3-buf LDS, depth-2 prefetch.
// Stage 2.5: relayout_kv: K,V^T -> fragment-major K'/V' (XCD-affine: bh -> XCD bh%8).
// Stage 3: flash attention (R15): barrier-free K-loop + 2-DEEP IN-WAVE PIPELINE:
//   body(it) = {issue V(it-1) | QK(it)->scCUR | K(it+1) prefetch | softmax(it-1) on scPREV
//   | PV(it-1)} -- every consumer is a full body behind its producer, so the per-region
//   in-order schedule never stalls on MFMA latency or load returns. scA/scB static alt.

typedef __attribute__((ext_vector_type(8))) short bf16x8;    // 8 bf16 = 4 VGPR (MFMA A/B frag)
typedef __attribute__((ext_vector_type(4))) float f32x4;     // 16x16 MFMA C/D frag
typedef __attribute__((ext_vector_type(16))) float f32x16;   // 32x32 MFMA C/D frag
typedef __attribute__((ext_vector_type(8))) unsigned short u16x8;

#define MFMA16(a, b, c) __builtin_amdgcn_mfma_f32_16x16x32_bf16((a), (b), (c), 0, 0, 0)
#define MFMA32(a, b, c) __builtin_amdgcn_mfma_f32_32x32x16_bf16((a), (b), (c), 0, 0, 0)
#define SWZ(row, colb) ((colb) ^ (((row) & 7) << 4))  // 128B-row swizzle

union U32x4BF {
  unsigned u[4];
  bf16x8 v;
};

__device__ __forceinline__ void gl_lds16(const void* g, void* l) {
  __builtin_amdgcn_global_load_lds(
      (__attribute__((address_space(1))) void*)const_cast<void*>(g),
      (__attribute__((address_space(3))) void*)l, 16, 0, 0);
}

__device__ __forceinline__ unsigned short f2bf(float x) {  // RNE f32->bf16
  unsigned int v = __float_as_uint(x);
  return (unsigned short)((v + 0x7fffu + ((v >> 16) & 1u)) >> 16);
}

// ---------------- Stage 1: f32 -> bf16 convert ----------------
__global__ __launch_bounds__(256) void cvt_all(
    const float* __restrict__ x, const float* __restrict__ wq,
    const float* __restrict__ wk, const float* __restrict__ wv,
    unsigned short* __restrict__ xb, unsigned short* __restrict__ wb) {
  int i = blockIdx.x * 256 + threadIdx.x;  // group-of-8 index; total 614400
  const float* s;
  unsigned short* d;
  int off;
  if (i < 393216)      { s = x;  d = xb;            off = i; }
  else if (i < 466944) { s = wq; d = wb;            off = i - 393216; }
  else if (i < 540672) { s = wk; d = wb + 589824;   off = i - 466944; }
  else                 { s = wv; d = wb + 1179648;  off = i - 540672; }
  const float4* sp = (const float4*)s + (size_t)off * 2;
  float4 a = sp[0], b2 = sp[1];
  u16x8 o;
  o[0] = f2bf(a.x); o[1] = f2bf(a.y); o[2] = f2bf(a.z); o[3] = f2bf(a.w);
  o[4] = f2bf(b2.x); o[5] = f2bf(b2.y); o[6] = f2bf(b2.z); o[7] = f2bf(b2.w);
  *((u16x8*)d + off) = o;
}

// ---------------- Stage 2: fused QKV projection (64x128 tile, BK=32) ----------------
__global__ __launch_bounds__(256) void proj_gemm(
    const unsigned short* __restrict__ xb, const unsigned short* __restrict__ wb,
    const float* __restrict__ bq, const float* __restrict__ bk, const float* __restrict__ bv,
    unsigned short* __restrict__ qw, unsigned short* __restrict__ kw,
    unsigned short* __restrict__ vw) {
  __shared__ __align__(16) char psmem[36864];  // 3 bufs x (A 4KB | B 8KB)
  const int t = threadIdx.x, lane = t & 63, w = t >> 6;
  const int lo = lane & 15, hi = lane >> 4;  // hi in 0..3
  const int mbase = blockIdx.x * 64;
  const int wsel = blockIdx.y / 6;
  const int nbase = (blockIdx.y % 6) * 128;
  const char* xc = (const char*)xb;
  const char* wmc = (const char*)(wb + (size_t)wsel * 589824);

  // staging decode: A chunk (1 per thread), B chunks (2 per thread)
  const int tA = t * 16;
  const int arA = tA >> 7, acA = (tA & 127) ^ ((arA & 7) << 4);
  const int mA = ((acA >> 6) << 5) + arA, kA = acA & 63;
  const int pB0 = t * 16, pB1 = t * 16 + 4096;
  const int rB0 = pB0 >> 7, cB0 = (pB0 & 127) ^ ((rB0 & 7) << 4);
  const int nB0 = ((cB0 >> 6) << 6) + rB0, kB0 = cB0 & 63;
  const int rB1 = pB1 >> 7, cB1 = (pB1 & 127) ^ ((rB1 & 7) << 4);
  const int nB1 = ((cB1 >> 6) << 6) + rB1, kB1 = cB1 & 63;

  const char* xa0 = xc + (size_t)(mbase + mA) * 1536 + kA;
  const char* wa0 = wmc + (size_t)(nbase + nB0) * 1536 + kB0;
  const char* wa1 = wmc + (size_t)(nbase + nB1) * 1536 + kB1;

#define PSTAGE(BUF)                              \
  do {                                           \
    char* lb = psmem + (BUF) * 12288;            \
    gl_lds16(xa0, lb + tA);                      \
    gl_lds16(wa0, lb + 4096 + pB0);              \
    gl_lds16(wa1, lb + 4096 + pB1);              \
    xa0 += 64; wa0 += 64; wa1 += 64;             \
  } while (0)

  f32x4 acc[4][2];
#pragma unroll
  for (int i = 0; i < 4; i++)
#pragma unroll
    for (int j = 0; j < 2; j++) acc[i][j] = (f32x4){0.f, 0.f, 0.f, 0.f};

  PSTAGE(0);
  PSTAGE(1);
  int cur = 0, sb = 2;
#pragma unroll 1
  for (int it = 0; it < 24; ++it) {
    if (it < 22) {
      PSTAGE(sb);
      asm volatile("s_waitcnt vmcnt(6)" ::: "memory");
    } else if (it == 22) {
      asm volatile("s_waitcnt vmcnt(3)" ::: "memory");
    } else {
      asm volatile("s_waitcnt vmcnt(0)" ::: "memory");
    }
    __builtin_amdgcn_s_barrier();
    const char* lA = psmem + cur * 12288;
    const char* lB = lA + 4096;

    bf16x8 af[4], bf[2];
#pragma unroll
    for (int mf = 0; mf < 4; mf++) {
      int row = mf * 16 + lo;  // 0..63
      af[mf] = *(const bf16x8*)(lA + (row & 31) * 128 +
                                ((((row >> 5) << 6) + hi * 16) ^ ((row & 7) << 4)));
    }
#pragma unroll
    for (int nf = 0; nf < 2; nf++) {
      int n = w * 32 + nf * 16 + lo;  // 0..127
      bf[nf] = *(const bf16x8*)(lB + (n & 63) * 128 +
                                ((((n >> 6) << 6) + hi * 16) ^ ((n & 7) << 4)));
    }

    __builtin_amdgcn_s_setprio(1);
    if (wsel == 2) {  // V: operand-swapped -> acc holds C^T (rows=n, cols=m)
#pragma unroll
      for (int mf = 0; mf < 4; mf++)
#pragma unroll
        for (int nf = 0; nf < 2; nf++) acc[mf][nf] = MFMA16(bf[nf], af[mf], acc[mf][nf]);
    } else {
#pragma unroll
      for (int mf = 0; mf < 4; mf++)
#pragma unroll
        for (int nf = 0; nf < 2; nf++) acc[mf][nf] = MFMA16(af[mf], bf[nf], acc[mf][nf]);
    }
    __builtin_amdgcn_s_setprio(0);
    __builtin_amdgcn_s_barrier();  // trailing barrier: depth-2 with 3 bufs race-free
    cur = (cur == 2) ? 0 : cur + 1;
    sb = (sb == 2) ? 0 : sb + 1;
  }
#undef PSTAGE

  const float QSCALE = 0.125f * 1.44269504089f;  // fold 1/sqrt(64) * log2(e)
  if (wsel == 2) {
#pragma unroll
    for (int nf = 0; nf < 2; nf++) {
#pragma unroll
      for (int mf = 0; mf < 4; mf++) {
#pragma unroll
        for (int r = 0; r < 4; r++) {
          int n = nbase + w * 32 + nf * 16 + hi * 4 + r;
          int m = mbase + mf * 16 + lo;
          int b_ = m >> 11, s = m & 2047;
          int h = n >> 6, wcol = n & 63;
          float val = acc[mf][nf][r] + bv[n];
          vw[(((size_t)b_ * 12 + h) * 64 + wcol) * 2048 + s] = f2bf(val);
        }
      }
    }
  } else {
    const float* bias = (wsel == 0) ? bq : bk;
#pragma unroll
    for (int nf = 0; nf < 2; nf++) {
      int n = nbase + w * 32 + nf * 16 + lo;
      float bv_ = bias[n];
      int h = n >> 6, wcol = n & 63;
#pragma unroll
      for (int mf = 0; mf < 4; mf++) {
#pragma unroll
        for (int r = 0; r < 4; r++) {
          int m = mbase + mf * 16 + hi * 4 + r;
          int b_ = m >> 11, s = m & 2047;
          float val = acc[mf][nf][r] + bv_;
          size_t bhh = (size_t)b_ * 12 + h;
          if (wsel == 0)
            qw[(bhh * 2048 + s) * 64 + wcol] = f2bf(val * QSCALE);
          else
            kw[(bhh * 2048 + s) * 64 + wcol] = f2bf(val);
        }
      }
    }
  }
}

// ---------------- Stage 2.5: relayout K,V^T -> fragment-major K',V' ----------------
// grid 384 blocks, XCD-affine: bh -> XCD bh%8 (same mapping as attn).
__global__ __launch_bounds__(256) void relayout_kv(
    const unsigned short* kw, const unsigned short* __restrict__ vwT,
    unsigned short* __restrict__ kx, unsigned short* vx) {
  __shared__ __align__(16) char rsm[32768];  // [0,16K) K' image | [16K,32K) V' image
  const int t = threadIdx.x;
  const int bid = blockIdx.x;
  const int xcd = bid & 7, sidx = bid >> 3;      // sidx 0..47
  const int bh = xcd + 8 * (sidx % 3);           // bh -> XCD bh%8
  const int ktq = sidx / 3;                      // 0..15
  const size_t bhb = (size_t)bh * 262144;  // per-bh byte stride in all four arrays
  const int kt0 = ktq * 4;

  // K stage: thread reads K[key][d0..d0+8) (16B row-major chunk), writes 16B frag-major LDS
  {
    const int key = t >> 3;      // key-in-tile 0..31
    const int d0 = (t & 7) * 8;  // 0..56
    const char* ksrc = (const char*)kw + bhb + (size_t)kt0 * 4096 + key * 128 + d0 * 2;
    char* kldst = rsm + (d0 >> 4) * 1024 + ((d0 >> 3) & 1) * 512 + key * 16;
#pragma unroll
    for (int c = 0; c < 4; c++)
      *(u16x8*)(kldst + c * 4096) = *(const u16x8*)(ksrc + c * 4096);
  }
  // V stage: thread reads V^T[w][s0..s0+8) (16B s-contiguous), writes 16B frag-major LDS
  {
    const int w = t >> 2;         // 0..63
    const int sl0 = (t & 3) * 8;  // s-in-tile base 0,8,16,24
    const char* vsrc = (const char*)vwT + bhb + (size_t)w * 4096 + (kt0 * 32 + sl0) * 2;
    char* vldst = rsm + 16384 + (w >> 5) * 2048 + ((sl0 >> 4) & 1) * 1024 +
                  ((sl0 >> 3) & 1) * 512 + (w & 31) * 16;
#pragma unroll
    for (int c = 0; c < 4; c++)
      *(u16x8*)(vldst + c * 4096) = *(const u16x8*)(vsrc + c * 64);
  }
  __syncthreads();  // LDS images complete; all this block's kw reads drained

  // copy-out: both images are contiguous 16KB runs of the global arrays
  char* kdst = (char*)kx + bhb + (size_t)ktq * 16384;
  char* vdst = (char*)vx + bhb + (size_t)ktq * 16384;
#pragma unroll
  for (int c = 0; c < 4; c++) {
    int lb = c * 4096 + t * 16;
    *(u16x8*)(kdst + lb) = *(const u16x8*)(rsm + lb);
    *(u16x8*)(vdst + lb) = *(const u16x8*)(rsm + 16384 + lb);
  }
}

// ---------------- Stage 3: flash attention (2-deep in-wave pipeline) ----------------
// grid 768 blocks (flat), XCD-affine. Block = 64 q-rows, waves = (wq q-half x wk key-half).
__global__ __launch_bounds__(256) void attn_kernel(
    const unsigned short* __restrict__ qw, const unsigned short* __restrict__ kx,
    const unsigned short* __restrict__ vx, const int* __restrict__ mask,
    float* __restrict__ out) {
  // [0,16384) epilogue O-staging (2 wq x 8KB) | [16384,16640) ballot bytes |
  // [16640,17152) lsum f32[128]: ((wq*32+q)*2 + wk)
  __shared__ __align__(16) char smem[17152];
  const int t = threadIdx.x, lane = t & 63, wave = t >> 6;
  const int wq = wave >> 1, wk = wave & 1;
  const int l31 = lane & 31, hl = lane >> 5;
  const int bid = blockIdx.x;
  const int xcd = bid & 7, sidx = bid >> 3;   // sidx 0..95
  const int bh = xcd + 8 * (sidx % 3);        // bh -> XCD bh%8
  const int qb = sidx / 3;                    // 0..31
  const int b = bh / 12, hh = bh - b * 12;

  // bit-pack mask: thread t packs keys [t*8, t*8+8) -> ballot bytes
  {
    const int* mb = mask + (size_t)b * 2048 + t * 8;
    int4 a0 = *(const int4*)mb;
    int4 a1 = *(const int4*)(mb + 4);
    unsigned by = (unsigned)(a0.x != 0) | ((unsigned)(a0.y != 0) << 1) |
                  ((unsigned)(a0.z != 0) << 2) | ((unsigned)(a0.w != 0) << 3) |
                  ((unsigned)(a1.x != 0) << 4) | ((unsigned)(a1.y != 0) << 5) |
                  ((unsigned)(a1.z != 0) << 6) | ((unsigned)(a1.w != 0) << 7);
    smem[16384 + t] = (char)by;
  }
  __syncthreads();
  // lane i holds the 32-key ballot of this wave's tile (i&31)
  const unsigned balv = *(const unsigned*)(smem + 16384 + (wk * 32 + l31) * 4);

  // Q B-frags: lane holds Q[q = l31 of wq-half][d = 16s + 8hl + j]
  bf16x8 qv[4];
  {
    int qrow = qb * 64 + wq * 32 + l31;
    const char* qp = (const char*)qw + ((size_t)bh * 2048 + qrow) * 128 + hl * 16;
#pragma unroll
    for (int s = 0; s < 4; s++) qv[s] = *(const bf16x8*)(qp + s * 32);
  }

  // fragment stream pointers (coalesced: lane*16 within 1KB chunks)
  const char* kp = (const char*)kx + (size_t)bh * 262144 + (size_t)wk * 131072 + lane * 16;
  const char* vp = (const char*)vx + (size_t)bh * 262144 + (size_t)wk * 131072 + lane * 16;

  f32x16 oacc[2], scA, scB;
#pragma unroll
  for (int wh = 0; wh < 2; wh++)
#pragma unroll
    for (int g = 0; g < 16; g++) oacc[wh][g] = 0.f;
  float lacc = 0.f;  // per-lane row-sum for q = l31 (this wave's hl/wk slice)
  bf16x8 v00, v01, v10, v11;
  bf16x8 ka0, ka1, ka2, ka3;

// softmax+PV for tile J_ using scores SCP_ and the V regs loaded this body
#define SMPV(J_, SCP_)                                                                   \
  {                                                                                      \
    unsigned bal_ = __builtin_amdgcn_readlane(balv, (J_));                               \
    if (bal_ != 0xFFFFFFFFu) {                                                           \
      _Pragma("unroll") for (int g = 0; g < 16; g++) {                                   \
        int key_ = (g & 3) + 8 * (g >> 2) + 4 * hl;                                      \
        if (!((bal_ >> key_) & 1)) SCP_[g] = -30000.f;                                   \
      }                                                                                  \
    }                                                                                    \
    _Pragma("unroll") for (int g = 0; g < 16; g++) {                                     \
      float e_;                                                                          \
      asm("v_exp_f32 %0, %1" : "=v"(e_) : "v"(SCP_[g]));                                 \
      SCP_[g] = e_;                                                                      \
    }                                                                                    \
    unsigned pk_[4][2];                                                                  \
    _Pragma("unroll") for (int m = 0; m < 4; m++) {                                      \
      asm("v_cvt_pk_bf16_f32 %0, %1, %2"                                                 \
          : "=v"(pk_[m][0]) : "v"(SCP_[4 * m]), "v"(SCP_[4 * m + 1]));                   \
      asm("v_cvt_pk_bf16_f32 %0, %1, %2"                                                 \
          : "=v"(pk_[m][1]) : "v"(SCP_[4 * m + 2]), "v"(SCP_[4 * m + 3]));               \
    }                                                                                    \
    U32x4BF apv_[2];                                                                     \
    _Pragma("unroll") for (int sp = 0; sp < 2; sp++)                                     \
        _Pragma("unroll") for (int cp = 0; cp < 2; cp++) {                               \
      unsigned xx_ = pk_[2 * sp][cp], yy_ = pk_[2 * sp + 1][cp];                         \
      asm("v_permlane32_swap_b32 %0, %1" : "+v"(xx_), "+v"(yy_));                        \
      apv_[sp].u[cp] = xx_;                                                              \
      apv_[sp].u[2 + cp] = yy_;                                                          \
    }                                                                                    \
    __builtin_amdgcn_s_setprio(1);                                                       \
    oacc[0] = MFMA32(apv_[0].v, v00, oacc[0]);                                           \
    oacc[0] = MFMA32(apv_[1].v, v01, oacc[0]);                                           \
    oacc[1] = MFMA32(apv_[0].v, v10, oacc[1]);                                           \
    oacc[1] = MFMA32(apv_[1].v, v11, oacc[1]);                                           \
    __builtin_amdgcn_s_setprio(0);                                                       \
    lacc += (((SCP_[0] + SCP_[1]) + (SCP_[2] + SCP_[3])) +                               \
             ((SCP_[4] + SCP_[5]) + (SCP_[6] + SCP_[7]))) +                              \
            (((SCP_[8] + SCP_[9]) + (SCP_[10] + SCP_[11])) +                             \
             ((SCP_[12] + SCP_[13]) + (SCP_[14] + SCP_[15])));                           \
  }

// body(IT_): issue V(IT_-1) -> QK(IT_)->SCQ_ -> prefetch K(IT_+1) -> SMPV(IT_-1, SCP_)
#define BODY(IT_, SCQ_, SCP_)                                                            \
  {                                                                                      \
    v00 = *(const bf16x8*)(vp);                                                          \
    v01 = *(const bf16x8*)(vp + 1024);                                                   \
    v10 = *(const bf16x8*)(vp + 2048);                                                   \
    v11 = *(const bf16x8*)(vp + 3072);                                                   \
    vp += 4096;                                                                          \
    _Pragma("unroll") for (int g = 0; g < 16; g++) SCQ_[g] = 0.f;                        \
    __builtin_amdgcn_s_setprio(1);                                                       \
    SCQ_ = MFMA32(ka0, qv[0], SCQ_);                                                     \
    SCQ_ = MFMA32(ka1, qv[1], SCQ_);                                                     \
    SCQ_ = MFMA32(ka2, qv[2], SCQ_);                                                     \
    SCQ_ = MFMA32(ka3, qv[3], SCQ_);                                                     \
    __builtin_amdgcn_s_setprio(0);                                                       \
    ka0 = *(const bf16x8*)(kp);                                                          \
    ka1 = *(const bf16x8*)(kp + 1024);                                                   \
    ka2 = *(const bf16x8*)(kp + 2048);                                                   \
    ka3 = *(const bf16x8*)(kp + 3072);                                                   \
    kp += 4096;                                                                          \
    SMPV((IT_) - 1, SCP_);                                                               \
  }

  // prologue: K(0), QK(0)->scA, prefetch K(1)
  ka0 = *(const bf16x8*)(kp);
  ka1 = *(const bf16x8*)(kp + 1024);
  ka2 = *(const bf16x8*)(kp + 2048);
  ka3 = *(const bf16x8*)(kp + 3072);
  kp += 4096;
#pragma unroll
  for (int g = 0; g < 16; g++) scA[g] = 0.f;
  scA = MFMA32(ka0, qv[0], scA);
  scA = MFMA32(ka1, qv[1], scA);
  scA = MFMA32(ka2, qv[2], scA);
  scA = MFMA32(ka3, qv[3], scA);
  ka0 = *(const bf16x8*)(kp);
  ka1 = *(const bf16x8*)(kp + 1024);
  ka2 = *(const bf16x8*)(kp + 2048);
  ka3 = *(const bf16x8*)(kp + 3072);
  kp += 4096;

#pragma unroll 1
  for (int itb = 1; itb < 31; itb += 2) {  // bodies 1..30: QK(it), finish(it-1)
    BODY(itb, scB, scA);
    BODY(itb + 1, scA, scB);
  }
  BODY(31, scB, scA);  // QK(31), finish(30); prefetches K(32) = adjacent valid bytes
  {                    // tail: V(31) + finish(31)
    v00 = *(const bf16x8*)(vp);
    v01 = *(const bf16x8*)(vp + 1024);
    v10 = *(const bf16x8*)(vp + 2048);
    v11 = *(const bf16x8*)(vp + 3072);
    SMPV(31, scB);
  }
#undef BODY
#undef SMPV

  // ---- epilogue: cross-wk reduce of O and l, then out = O / l ----
  lacc += __shfl_xor(lacc, 32);  // combine hl halves; all lanes hold sum for q=l31 (wk half)
  if (lane < 32)
    *(float*)(smem + 16640 + (((wq * 32 + l31) << 1) + wk) * 4) = lacc;
  if (wk == 1) {  // partial O as [w][q] f32 into [0,16384)
#pragma unroll
    for (int wh = 0; wh < 2; wh++) {
      int vrow = wh * 32 + l31;
#pragma unroll
      for (int m = 0; m < 4; m++) {
        f32x4 part = (f32x4){oacc[wh][4 * m], oacc[wh][4 * m + 1],
                             oacc[wh][4 * m + 2], oacc[wh][4 * m + 3]};
        *(f32x4*)(smem + wq * 8192 + vrow * 128 + SWZ(vrow, hl * 16 + m * 32)) = part;
      }
    }
  }
  __syncthreads();
  if (wk == 0) {
    float linv[16];
#pragma unroll
    for (int g = 0; g < 16; g++) {
      int qrow = 4 * hl + (g & 3) + 8 * (g >> 2);
      float2 lp = *(const float2*)(smem + 16640 + ((wq * 32 + qrow) << 3));
      linv[g] = __builtin_amdgcn_rcpf(lp.x + lp.y);
    }
#pragma unroll
    for (int wh = 0; wh < 2; wh++) {
      int vrow = wh * 32 + l31;
#pragma unroll
      for (int m = 0; m < 4; m++) {
        f32x4 part = *(const f32x4*)(smem + wq * 8192 + vrow * 128 + SWZ(vrow, hl * 16 + m * 32));
#pragma unroll
        for (int r = 0; r < 4; r++) {
          int g = 4 * m + r;
          int qrow = 4 * hl + r + 8 * m;
          float val = (oacc[wh][g] + part[r]) * linv[g];
          out[((size_t)b * 2048 + qb * 64 + wq * 32 + qrow) * 768 + hh * 64 + wh * 32 + l31] =
              val;
        }
      }
    }
  }
}

// ---------------- launch ----------------
extern "C" void kernel_launch(void* const* d_in, const int* in_sizes, int n_in,
                              void* d_out, int out_size, void* d_ws, size_t ws_size,
                              hipStream_t stream) {
  (void)in_sizes; (void)n_in; (void)out_size; (void)ws_size;
  const float* x  = (const float*)d_in[0];
  const float* Wq = (const float*)d_in[1];
  const float* bq = (const float*)d_in[2];
  const float* Wk = (const float*)d_in[3];
  const float* bk = (const float*)d_in[4];
  const float* Wv = (const float*)d_in[5];
  const float* bv = (const float*)d_in[6];
  const int* mask = (const int*)d_in[7];
  float* out = (float*)d_out;

  char* ws = (char*)d_ws;
  unsigned short* xb  = (unsigned short*)(ws);             // 4096x768 bf16 (6291456 B)
  unsigned short* wb  = (unsigned short*)(ws + 6291456);   // 3x 768x768 bf16 (3538944 B)
  unsigned short* qw  = (unsigned short*)(ws + 9830400);   // Q (B,H,S,W)
  unsigned short* kw  = (unsigned short*)(ws + 16121856);  // K (B,H,S,W) [pre-relayout]
  unsigned short* vwT = (unsigned short*)(ws + 22413312);  // V^T (B,H,W,S)
  unsigned short* kx  = (unsigned short*)(ws);             // K' frag-major (over xb, dead)
  unsigned short* vx  = (unsigned short*)(ws + 16121856);  // V' frag-major (over kw, dead)

  cvt_all<<<2400, 256, 0, stream>>>(x, Wq, Wk, Wv, xb, wb);
  proj_gemm<<<dim3(64, 18), 256, 0, stream>>>(xb, wb, bq, bk, bv, qw, kw, vwT);
  relayout_kv<<<384, 256, 0, stream>>>(kw, vwT, kx, vx);
  attn_kernel<<<768, 256, 0, stream>>>(qw, kx, vx, mask, out);
}

// Round 16
// 81.179 us; speedup vs baseline: 1.0878x; 1.0167x over previous
//
#include <hip/hip_runtime.h>
#include <hip/hip_bf16.h>
#include <stdint.h>

// BERT self-attention fwd: B=2, S=2048, D=768, H=12, W=64. f32 in/out, bf16 MFMA inside.
// Stage 1: cvt x,Wq,Wk,Wv -> bf16.
// Stage 2: QKV projection GEMM, 64x128 tile, BK=32, 3-buf LDS, depth-2 prefetch.
// Stage 2.5: relayout_kv: K,V^T -> fragment-major K'/V' (XCD-affine: bh -> XCD bh%8).
// Stage 3: flash attention (R16): barrier-free + 2-deep in-wave pipeline + WAVE-UNIFORM
//   MASK HOIST: nomask = __all(ballots == ~0) decided once; the hot loop instantiation has
//   ZERO branches in the body -> one basic block -> scheduler interleaves softmax(it-1)
//   VALU into QK(it)'s MFMA-chain latency shadow. Masked path is branchless selects.

typedef __attribute__((ext_vector_type(8))) short bf16x8;    // 8 bf16 = 4 VGPR (MFMA A/B frag)
typedef __attribute__((ext_vector_type(4))) float f32x4;     // 16x16 MFMA C/D frag
typedef __attribute__((ext_vector_type(16))) float f32x16;   // 32x32 MFMA C/D frag
typedef __attribute__((ext_vector_type(8))) unsigned short u16x8;

#define MFMA16(a, b, c) __builtin_amdgcn_mfma_f32_16x16x32_bf16((a), (b), (c), 0, 0, 0)
#define MFMA32(a, b, c) __builtin_amdgcn_mfma_f32_32x32x16_bf16((a), (b), (c), 0, 0, 0)
#define SWZ(row, colb) ((colb) ^ (((row) & 7) << 4))  // 128B-row swizzle

union U32x4BF {
  unsigned u[4];
  bf16x8 v;
};

__device__ __forceinline__ void gl_lds16(const void* g, void* l) {
  __builtin_amdgcn_global_load_lds(
      (__attribute__((address_space(1))) void*)const_cast<void*>(g),
      (__attribute__((address_space(3))) void*)l, 16, 0, 0);
}

__device__ __forceinline__ unsigned short f2bf(float x) {  // RNE f32->bf16
  unsigned int v = __float_as_uint(x);
  return (unsigned short)((v + 0x7fffu + ((v >> 16) & 1u)) >> 16);
}

// ---------------- Stage 1: f32 -> bf16 convert ----------------
__global__ __launch_bounds__(256) void cvt_all(
    const float* __restrict__ x, const float* __restrict__ wq,
    const float* __restrict__ wk, const float* __restrict__ wv,
    unsigned short* __restrict__ xb, unsigned short* __restrict__ wb) {
  int i = blockIdx.x * 256 + threadIdx.x;  // group-of-8 index; total 614400
  const float* s;
  unsigned short* d;
  int off;
  if (i < 393216)      { s = x;  d = xb;            off = i; }
  else if (i < 466944) { s = wq; d = wb;            off = i - 393216; }
  else if (i < 540672) { s = wk; d = wb + 589824;   off = i - 466944; }
  else                 { s = wv; d = wb + 1179648;  off = i - 540672; }
  const float4* sp = (const float4*)s + (size_t)off * 2;
  float4 a = sp[0], b2 = sp[1];
  u16x8 o;
  o[0] = f2bf(a.x); o[1] = f2bf(a.y); o[2] = f2bf(a.z); o[3] = f2bf(a.w);
  o[4] = f2bf(b2.x); o[5] = f2bf(b2.y); o[6] = f2bf(b2.z); o[7] = f2bf(b2.w);
  *((u16x8*)d + off) = o;
}

// ---------------- Stage 2: fused QKV projection (64x128 tile, BK=32) ----------------
__global__ __launch_bounds__(256) void proj_gemm(
    const unsigned short* __restrict__ xb, const unsigned short* __restrict__ wb,
    const float* __restrict__ bq, const float* __restrict__ bk, const float* __restrict__ bv,
    unsigned short* __restrict__ qw, unsigned short* __restrict__ kw,
    unsigned short* __restrict__ vw) {
  __shared__ __align__(16) char psmem[36864];  // 3 bufs x (A 4KB | B 8KB)
  const int t = threadIdx.x, lane = t & 63, w = t >> 6;
  const int lo = lane & 15, hi = lane >> 4;  // hi in 0..3
  const int mbase = blockIdx.x * 64;
  const int wsel = blockIdx.y / 6;
  const int nbase = (blockIdx.y % 6) * 128;
  const char* xc = (const char*)xb;
  const char* wmc = (const char*)(wb + (size_t)wsel * 589824);

  // staging decode: A chunk (1 per thread), B chunks (2 per thread)
  const int tA = t * 16;
  const int arA = tA >> 7, acA = (tA & 127) ^ ((arA & 7) << 4);
  const int mA = ((acA >> 6) << 5) + arA, kA = acA & 63;
  const int pB0 = t * 16, pB1 = t * 16 + 4096;
  const int rB0 = pB0 >> 7, cB0 = (pB0 & 127) ^ ((rB0 & 7) << 4);
  const int nB0 = ((cB0 >> 6) << 6) + rB0, kB0 = cB0 & 63;
  const int rB1 = pB1 >> 7, cB1 = (pB1 & 127) ^ ((rB1 & 7) << 4);
  const int nB1 = ((cB1 >> 6) << 6) + rB1, kB1 = cB1 & 63;

  const char* xa0 = xc + (size_t)(mbase + mA) * 1536 + kA;
  const char* wa0 = wmc + (size_t)(nbase + nB0) * 1536 + kB0;
  const char* wa1 = wmc + (size_t)(nbase + nB1) * 1536 + kB1;

#define PSTAGE(BUF)                              \
  do {                                           \
    char* lb = psmem + (BUF) * 12288;            \
    gl_lds16(xa0, lb + tA);                      \
    gl_lds16(wa0, lb + 4096 + pB0);              \
    gl_lds16(wa1, lb + 4096 + pB1);              \
    xa0 += 64; wa0 += 64; wa1 += 64;             \
  } while (0)

  f32x4 acc[4][2];
#pragma unroll
  for (int i = 0; i < 4; i++)
#pragma unroll
    for (int j = 0; j < 2; j++) acc[i][j] = (f32x4){0.f, 0.f, 0.f, 0.f};

  PSTAGE(0);
  PSTAGE(1);
  int cur = 0, sb = 2;
#pragma unroll 1
  for (int it = 0; it < 24; ++it) {
    if (it < 22) {
      PSTAGE(sb);
      asm volatile("s_waitcnt vmcnt(6)" ::: "memory");
    } else if (it == 22) {
      asm volatile("s_waitcnt vmcnt(3)" ::: "memory");
    } else {
      asm volatile("s_waitcnt vmcnt(0)" ::: "memory");
    }
    __builtin_amdgcn_s_barrier();
    const char* lA = psmem + cur * 12288;
    const char* lB = lA + 4096;

    bf16x8 af[4], bf[2];
#pragma unroll
    for (int mf = 0; mf < 4; mf++) {
      int row = mf * 16 + lo;  // 0..63
      af[mf] = *(const bf16x8*)(lA + (row & 31) * 128 +
                                ((((row >> 5) << 6) + hi * 16) ^ ((row & 7) << 4)));
    }
#pragma unroll
    for (int nf = 0; nf < 2; nf++) {
      int n = w * 32 + nf * 16 + lo;  // 0..127
      bf[nf] = *(const bf16x8*)(lB + (n & 63) * 128 +
                                ((((n >> 6) << 6) + hi * 16) ^ ((n & 7) << 4)));
    }

    __builtin_amdgcn_s_setprio(1);
    if (wsel == 2) {  // V: operand-swapped -> acc holds C^T (rows=n, cols=m)
#pragma unroll
      for (int mf = 0; mf < 4; mf++)
#pragma unroll
        for (int nf = 0; nf < 2; nf++) acc[mf][nf] = MFMA16(bf[nf], af[mf], acc[mf][nf]);
    } else {
#pragma unroll
      for (int mf = 0; mf < 4; mf++)
#pragma unroll
        for (int nf = 0; nf < 2; nf++) acc[mf][nf] = MFMA16(af[mf], bf[nf], acc[mf][nf]);
    }
    __builtin_amdgcn_s_setprio(0);
    __builtin_amdgcn_s_barrier();  // trailing barrier: depth-2 with 3 bufs race-free
    cur = (cur == 2) ? 0 : cur + 1;
    sb = (sb == 2) ? 0 : sb + 1;
  }
#undef PSTAGE

  const float QSCALE = 0.125f * 1.44269504089f;  // fold 1/sqrt(64) * log2(e)
  if (wsel == 2) {
#pragma unroll
    for (int nf = 0; nf < 2; nf++) {
#pragma unroll
      for (int mf = 0; mf < 4; mf++) {
#pragma unroll
        for (int r = 0; r < 4; r++) {
          int n = nbase + w * 32 + nf * 16 + hi * 4 + r;
          int m = mbase + mf * 16 + lo;
          int b_ = m >> 11, s = m & 2047;
          int h = n >> 6, wcol = n & 63;
          float val = acc[mf][nf][r] + bv[n];
          vw[(((size_t)b_ * 12 + h) * 64 + wcol) * 2048 + s] = f2bf(val);
        }
      }
    }
  } else {
    const float* bias = (wsel == 0) ? bq : bk;
#pragma unroll
    for (int nf = 0; nf < 2; nf++) {
      int n = nbase + w * 32 + nf * 16 + lo;
      float bv_ = bias[n];
      int h = n >> 6, wcol = n & 63;
#pragma unroll
      for (int mf = 0; mf < 4; mf++) {
#pragma unroll
        for (int r = 0; r < 4; r++) {
          int m = mbase + mf * 16 + hi * 4 + r;
          int b_ = m >> 11, s = m & 2047;
          float val = acc[mf][nf][r] + bv_;
          size_t bhh = (size_t)b_ * 12 + h;
          if (wsel == 0)
            qw[(bhh * 2048 + s) * 64 + wcol] = f2bf(val * QSCALE);
          else
            kw[(bhh * 2048 + s) * 64 + wcol] = f2bf(val);
        }
      }
    }
  }
}

// ---------------- Stage 2.5: relayout K,V^T -> fragment-major K',V' ----------------
// grid 384 blocks, XCD-affine: bh -> XCD bh%8 (same mapping as attn).
__global__ __launch_bounds__(256) void relayout_kv(
    const unsigned short* kw, const unsigned short* __restrict__ vwT,
    unsigned short* __restrict__ kx, unsigned short* vx) {
  __shared__ __align__(16) char rsm[32768];  // [0,16K) K' image | [16K,32K) V' image
  const int t = threadIdx.x;
  const int bid = blockIdx.x;
  const int xcd = bid & 7, sidx = bid >> 3;      // sidx 0..47
  const int bh = xcd + 8 * (sidx % 3);           // bh -> XCD bh%8
  const int ktq = sidx / 3;                      // 0..15
  const size_t bhb = (size_t)bh * 262144;  // per-bh byte stride in all four arrays
  const int kt0 = ktq * 4;

  // K stage: thread reads K[key][d0..d0+8) (16B row-major chunk), writes 16B frag-major LDS
  {
    const int key = t >> 3;      // key-in-tile 0..31
    const int d0 = (t & 7) * 8;  // 0..56
    const char* ksrc = (const char*)kw + bhb + (size_t)kt0 * 4096 + key * 128 + d0 * 2;
    char* kldst = rsm + (d0 >> 4) * 1024 + ((d0 >> 3) & 1) * 512 + key * 16;
#pragma unroll
    for (int c = 0; c < 4; c++)
      *(u16x8*)(kldst + c * 4096) = *(const u16x8*)(ksrc + c * 4096);
  }
  // V stage: thread reads V^T[w][s0..s0+8) (16B s-contiguous), writes 16B frag-major LDS
  {
    const int w = t >> 2;         // 0..63
    const int sl0 = (t & 3) * 8;  // s-in-tile base 0,8,16,24
    const char* vsrc = (const char*)vwT + bhb + (size_t)w * 4096 + (kt0 * 32 + sl0) * 2;
    char* vldst = rsm + 16384 + (w >> 5) * 2048 + ((sl0 >> 4) & 1) * 1024 +
                  ((sl0 >> 3) & 1) * 512 + (w & 31) * 16;
#pragma unroll
    for (int c = 0; c < 4; c++)
      *(u16x8*)(vldst + c * 4096) = *(const u16x8*)(vsrc + c * 64);
  }
  __syncthreads();  // LDS images complete; all this block's kw reads drained

  // copy-out: both images are contiguous 16KB runs of the global arrays
  char* kdst = (char*)kx + bhb + (size_t)ktq * 16384;
  char* vdst = (char*)vx + bhb + (size_t)ktq * 16384;
#pragma unroll
  for (int c = 0; c < 4; c++) {
    int lb = c * 4096 + t * 16;
    *(u16x8*)(kdst + lb) = *(const u16x8*)(rsm + lb);
    *(u16x8*)(vdst + lb) = *(const u16x8*)(rsm + 16384 + lb);
  }
}

// ---------------- Stage 3: flash attention (2-deep pipeline, branch-free hot loop) -----
// grid 768 blocks (flat), XCD-affine. Block = 64 q-rows, waves = (wq q-half x wk key-half).
__global__ __launch_bounds__(256) void attn_kernel(
    const unsigned short* __restrict__ qw, const unsigned short* __restrict__ kx,
    const unsigned short* __restrict__ vx, const int* __restrict__ mask,
    float* __restrict__ out) {
  // [0,16384) epilogue O-staging (2 wq x 8KB) | [16384,16640) ballot bytes |
  // [16640,17152) lsum f32[128]: ((wq*32+q)*2 + wk)
  __shared__ __align__(16) char smem[17152];
  const int t = threadIdx.x, lane = t & 63, wave = t >> 6;
  const int wq = wave >> 1, wk = wave & 1;
  const int l31 = lane & 31, hl = lane >> 5;
  const int bid = blockIdx.x;
  const int xcd = bid & 7, sidx = bid >> 3;   // sidx 0..95
  const int bh = xcd + 8 * (sidx % 3);        // bh -> XCD bh%8
  const int qb = sidx / 3;                    // 0..31
  const int b = bh / 12, hh = bh - b * 12;

  // bit-pack mask: thread t packs keys [t*8, t*8+8) -> ballot bytes
  {
    const int* mb = mask + (size_t)b * 2048 + t * 8;
    int4 a0 = *(const int4*)mb;
    int4 a1 = *(const int4*)(mb + 4);
    unsigned by = (unsigned)(a0.x != 0) | ((unsigned)(a0.y != 0) << 1) |
                  ((unsigned)(a0.z != 0) << 2) | ((unsigned)(a0.w != 0) << 3) |
                  ((unsigned)(a1.x != 0) << 4) | ((unsigned)(a1.y != 0) << 5) |
                  ((unsigned)(a1.z != 0) << 6) | ((unsigned)(a1.w != 0) << 7);
    smem[16384 + t] = (char)by;
  }
  __syncthreads();
  // lane i holds the 32-key ballot of this wave's tile (i&31)
  const unsigned balv = *(const unsigned*)(smem + 16384 + (wk * 32 + l31) * 4);
  // wave-uniform: no key anywhere in this batch row is masked -> branch-free hot loop
  const bool nomask = __all((int)(balv == 0xFFFFFFFFu));

  // Q B-frags: lane holds Q[q = l31 of wq-half][d = 16s + 8hl + j]
  bf16x8 qv[4];
  {
    int qrow = qb * 64 + wq * 32 + l31;
    const char* qp = (const char*)qw + ((size_t)bh * 2048 + qrow) * 128 + hl * 16;
#pragma unroll
    for (int s = 0; s < 4; s++) qv[s] = *(const bf16x8*)(qp + s * 32);
  }

  // fragment stream pointers (coalesced: lane*16 within 1KB chunks)
  const char* kp = (const char*)kx + (size_t)bh * 262144 + (size_t)wk * 131072 + lane * 16;
  const char* vp = (const char*)vx + (size_t)bh * 262144 + (size_t)wk * 131072 + lane * 16;

  f32x16 oacc[2], scA, scB;
#pragma unroll
  for (int wh = 0; wh < 2; wh++)
#pragma unroll
    for (int g = 0; g < 16; g++) oacc[wh][g] = 0.f;
  float lacc = 0.f;  // per-lane row-sum for q = l31 (this wave's hl/wk slice)
  bf16x8 v00, v01, v10, v11;
  bf16x8 ka0, ka1, ka2, ka3;

// softmax+PV for tile J_ using scores SCP_ and the V regs loaded this body.
// DOMASK_ is a compile-time 0/1: the 0-instantiation has NO branch (single basic block).
#define SMPV(J_, SCP_, DOMASK_)                                                          \
  {                                                                                      \
    if (DOMASK_) {                                                                       \
      unsigned bal_ = __builtin_amdgcn_readlane(balv, (J_));                             \
      _Pragma("unroll") for (int g = 0; g < 16; g++) {                                   \
        int key_ = (g & 3) + 8 * (g >> 2) + 4 * hl;                                      \
        SCP_[g] = ((bal_ >> key_) & 1) ? SCP_[g] : -30000.f;                             \
      }                                                                                  \
    }                                                                                    \
    _Pragma("unroll") for (int g = 0; g < 16; g++) {                                     \
      float e_;                                                                          \
      asm("v_exp_f32 %0, %1" : "=v"(e_) : "v"(SCP_[g]));                                 \
      SCP_[g] = e_;                                                                      \
    }                                                                                    \
    unsigned pk_[4][2];                                                                  \
    _Pragma("unroll") for (int m = 0; m < 4; m++) {                                      \
      asm("v_cvt_pk_bf16_f32 %0, %1, %2"                                                 \
          : "=v"(pk_[m][0]) : "v"(SCP_[4 * m]), "v"(SCP_[4 * m + 1]));                   \
      asm("v_cvt_pk_bf16_f32 %0, %1, %2"                                                 \
          : "=v"(pk_[m][1]) : "v"(SCP_[4 * m + 2]), "v"(SCP_[4 * m + 3]));               \
    }                                                                                    \
    U32x4BF apv_[2];                                                                     \
    _Pragma("unroll") for (int sp = 0; sp < 2; sp++)                                     \
        _Pragma("unroll") for (int cp = 0; cp < 2; cp++) {                               \
      unsigned xx_ = pk_[2 * sp][cp], yy_ = pk_[2 * sp + 1][cp];                         \
      asm("v_permlane32_swap_b32 %0, %1" : "+v"(xx_), "+v"(yy_));                        \
      apv_[sp].u[cp] = xx_;                                                              \
      apv_[sp].u[2 + cp] = yy_;                                                          \
    }                                                                                    \
    __builtin_amdgcn_s_setprio(1);                                                       \
    oacc[0] = MFMA32(apv_[0].v, v00, oacc[0]);                                           \
    oacc[0] = MFMA32(apv_[1].v, v01, oacc[0]);                                           \
    oacc[1] = MFMA32(apv_[0].v, v10, oacc[1]);                                           \
    oacc[1] = MFMA32(apv_[1].v, v11, oacc[1]);                                           \
    __builtin_amdgcn_s_setprio(0);                                                       \
    lacc += (((SCP_[0] + SCP_[1]) + (SCP_[2] + SCP_[3])) +                               \
             ((SCP_[4] + SCP_[5]) + (SCP_[6] + SCP_[7]))) +                              \
            (((SCP_[8] + SCP_[9]) + (SCP_[10] + SCP_[11])) +                             \
             ((SCP_[12] + SCP_[13]) + (SCP_[14] + SCP_[15])));                           \
  }

// body(IT_): issue V(IT_-1) -> QK(IT_)->SCQ_ -> prefetch K(IT_+1) -> SMPV(IT_-1, SCP_)
#define BODY(IT_, SCQ_, SCP_, DOMASK_)                                                   \
  {                                                                                      \
    v00 = *(const bf16x8*)(vp);                                                          \
    v01 = *(const bf16x8*)(vp + 1024);                                                   \
    v10 = *(const bf16x8*)(vp + 2048);                                                   \
    v11 = *(const bf16x8*)(vp + 3072);                                                   \
    vp += 4096;                                                                          \
    _Pragma("unroll") for (int g = 0; g < 16; g++) SCQ_[g] = 0.f;                        \
    __builtin_amdgcn_s_setprio(1);                                                       \
    SCQ_ = MFMA32(ka0, qv[0], SCQ_);                                                     \
    SCQ_ = MFMA32(ka1, qv[1], SCQ_);                                                     \
    SCQ_ = MFMA32(ka2, qv[2], SCQ_);                                                     \
    SCQ_ = MFMA32(ka3, qv[3], SCQ_);                                                     \
    __builtin_amdgcn_s_setprio(0);                                                       \
    ka0 = *(const bf16x8*)(kp);                                                          \
    ka1 = *(const bf16x8*)(kp + 1024);                                                   \
    ka2 = *(const bf16x8*)(kp + 2048);                                                   \
    ka3 = *(const bf16x8*)(kp + 3072);                                                   \
    kp += 4096;                                                                          \
    SMPV((IT_) - 1, SCP_, DOMASK_);                                                      \
  }

// full pipelined loop, one instantiation per mask mode
#define RUNLOOP(DOMASK_)                                                                 \
  {                                                                                      \
    _Pragma("unroll 1") for (int itb = 1; itb < 31; itb += 2) {                          \
      BODY(itb, scB, scA, DOMASK_);                                                      \
      BODY(itb + 1, scA, scB, DOMASK_);                                                  \
    }                                                                                    \
    BODY(31, scB, scA, DOMASK_);                                                         \
    v00 = *(const bf16x8*)(vp);                                                          \
    v01 = *(const bf16x8*)(vp + 1024);                                                   \
    v10 = *(const bf16x8*)(vp + 2048);                                                   \
    v11 = *(const bf16x8*)(vp + 3072);                                                   \
    SMPV(31, scB, DOMASK_);                                                              \
  }

  // prologue: K(0), QK(0)->scA, prefetch K(1)
  ka0 = *(const bf16x8*)(kp);
  ka1 = *(const bf16x8*)(kp + 1024);
  ka2 = *(const bf16x8*)(kp + 2048);
  ka3 = *(const bf16x8*)(kp + 3072);
  kp += 4096;
#pragma unroll
  for (int g = 0; g < 16; g++) scA[g] = 0.f;
  scA = MFMA32(ka0, qv[0], scA);
  scA = MFMA32(ka1, qv[1], scA);
  scA = MFMA32(ka2, qv[2], scA);
  scA = MFMA32(ka3, qv[3], scA);
  ka0 = *(const bf16x8*)(kp);
  ka1 = *(const bf16x8*)(kp + 1024);
  ka2 = *(const bf16x8*)(kp + 2048);
  ka3 = *(const bf16x8*)(kp + 3072);
  kp += 4096;

  if (nomask) {
    RUNLOOP(0)  // hot path: zero branches per body -> scheduler interleaves freely
  } else {
    RUNLOOP(1)  // branchless per-element selects, exact mask semantics
  }
#undef RUNLOOP
#undef BODY
#undef SMPV

  // ---- epilogue: cross-wk reduce of O and l, then out = O / l ----
  lacc += __shfl_xor(lacc, 32);  // combine hl halves; all lanes hold sum for q=l31 (wk half)
  if (lane < 32)
    *(float*)(smem + 16640 + (((wq * 32 + l31) << 1) + wk) * 4) = lacc;
  if (wk == 1) {  // partial O as [w][q] f32 into [0,16384)
#pragma unroll
    for (int wh = 0; wh < 2; wh++) {
      int vrow = wh * 32 + l31;
#pragma unroll
      for (int m = 0; m < 4; m++) {
        f32x4 part = (f32x4){oacc[wh][4 * m], oacc[wh][4 * m + 1],
                             oacc[wh][4 * m + 2], oacc[wh][4 * m + 3]};
        *(f32x4*)(smem + wq * 8192 + vrow * 128 + SWZ(vrow, hl * 16 + m * 32)) = part;
      }
    }
  }
  __syncthreads();
  if (wk == 0) {
    float linv[16];
#pragma unroll
    for (int g = 0; g < 16; g++) {
      int qrow = 4 * hl + (g & 3) + 8 * (g >> 2);
      float2 lp = *(const float2*)(smem + 16640 + ((wq * 32 + qrow) << 3));
      linv[g] = __builtin_amdgcn_rcpf(lp.x + lp.y);
    }
#pragma unroll
    for (int wh = 0; wh < 2; wh++) {
      int vrow = wh * 32 + l31;
#pragma unroll
      for (int m = 0; m < 4; m++) {
        f32x4 part = *(const f32x4*)(smem + wq * 8192 + vrow * 128 + SWZ(vrow, hl * 16 + m * 32));
#pragma unroll
        for (int r = 0; r < 4; r++) {
          int g = 4 * m + r;
          int qrow = 4 * hl + r + 8 * m;
          float val = (oacc[wh][g] + part[r]) * linv[g];
          out[((size_t)b * 2048 + qb * 64 + wq * 32 + qrow) * 768 + hh * 64 + wh * 32 + l31] =
              val;
        }
      }
    }
  }
}

// ---------------- launch ----------------
extern "C" void kernel_launch(void* const* d_in, const int* in_sizes, int n_in,
                              void* d_out, int out_size, void* d_ws, size_t ws_size,
                              hipStream_t stream) {
  (void)in_sizes; (void)n_in; (void)out_size; (void)ws_size;
  const float* x  = (const float*)d_in[0];
  const float* Wq = (const float*)d_in[1];
  const float* bq = (const float*)d_in[2];
  const float* Wk = (const float*)d_in[3];
  const float* bk = (const float*)d_in[4];
  const float* Wv = (const float*)d_in[5];
  const float* bv = (const float*)d_in[6];
  const int* mask = (const int*)d_in[7];
  float* out = (float*)d_out;

  char* ws = (char*)d_ws;
  unsigned short* xb  = (unsigned short*)(ws);             // 4096x768 bf16 (6291456 B)
  unsigned short* wb  = (unsigned short*)(ws + 6291456);   // 3x 768x768 bf16 (3538944 B)
  unsigned short* qw  = (unsigned short*)(ws + 9830400);   // Q (B,H,S,W)
  unsigned short* kw  = (unsigned short*)(ws + 16121856);  // K (B,H,S,W) [pre-relayout]
  unsigned short* vwT = (unsigned short*)(ws + 22413312);  // V^T (B,H,W,S)
  unsigned short* kx  = (unsigned short*)(ws);             // K' frag-major (over xb, dead)
  unsigned short* vx  = (unsigned short*)(ws + 16121856);  // V' frag-major (over kw, dead)

  cvt_all<<<2400, 256, 0, stream>>>(x, Wq, Wk, Wv, xb, wb);
  proj_gemm<<<dim3(64, 18), 256, 0, stream>>>(xb, wb, bq, bk, bv, qw, kw, vwT);
  relayout_kv<<<384, 256, 0, stream>>>(kw, vwT, kx, vx);
  attn_kernel<<<768, 256, 0, stream>>>(qw, kx, vx, mask, out);
}